// Round 5
// baseline (10826.350 us; speedup 1.0000x reference)
//
#include <hip/hip_runtime.h>

// RecurrentTransformerEncoder on MI355X — round 13: single fix over round 12.
// Round 12's phase2_seq compiled at 64 VGPR (no min-waves hint -> compiler
// targeted 8 waves/EU) while the FFN phase has ~100 live values -> MFMA
// accumulators spilled to scratch (FETCH +2.1GB, MfmaUtil 1.5%, 9.5ms).
// __launch_bounds__(1024, 4) caps occupancy at exactly our one-block/CU and
// raises the VGPR budget to 128 -> no spills. Everything else byte-identical
// to the correctness-verified round-12 kernel.
// B=64, T=16, SEG=50, E=D=512, H=8, DH=64, F=2048.

#define NB   64
#define NT   16
#define SEGL 50
#define DMODEL 512
#define DFF  2048
#define NHEAD 8
#define DHEAD 64

typedef unsigned short ushort_t;
typedef __attribute__((ext_vector_type(8))) short bfrag;   // 8 bf16 (4 VGPRs)
typedef __attribute__((ext_vector_type(4))) float ffrag;   // 4 fp32 acc

__device__ __forceinline__ ushort_t f2b(float x) {
    union { float f; unsigned u; } c; c.f = x;
    unsigned r = c.u + 0x7fffu + ((c.u >> 16) & 1u);
    return (ushort_t)(r >> 16);
}

#define GLOAD_LDS16(g, l) __builtin_amdgcn_global_load_lds( \
    (const __attribute__((address_space(1))) void*)(g),      \
    (__attribute__((address_space(3))) void*)(l), 16, 0, 0)

#define MFMA16(a, b, c) __builtin_amdgcn_mfma_f32_16x16x32_bf16(a, b, c, 0, 0, 0)

// ---------------------------------------------------------------------------
// MFMA GEMM (LDS-staged, BK=64 dbuf): C = relu?(A @ Bt^T), bf16.  (phase 1)
// ---------------------------------------------------------------------------
template<int BM, int BN, int WROWS, int WCOLS>
__global__ __launch_bounds__(256) void mfma_gemm(
    const ushort_t* __restrict__ A, int agrp, long long astride,
    const ushort_t* __restrict__ Bt, ushort_t* __restrict__ C,
    int M, int N, int K, int relu)
{
    constexpr int WM = BM / WROWS, WN = BN / WCOLS;
    constexpr int SM = WM / 16, SN = WN / 16;
    constexpr int NSUBA = BM / 16, NSUBB = BN / 16;
    constexpr int NSUB = NSUBA + NSUBB;
    constexpr int NINST = NSUB * 2;
    constexpr int IPW = NINST / 4;
    constexpr int BUFS = NSUB * 1024;
    constexpr int EST = WN + 8;
    constexpr int LDS_KLOOP = 2 * BUFS;
    constexpr int LDS_EPI   = 4 * WM * EST;
    constexpr int LDS_SZ = LDS_KLOOP > LDS_EPI ? LDS_KLOOP : LDS_EPI;
    __shared__ ushort_t lds[LDS_SZ];

    const int tid = threadIdx.x;
    const int wave = tid >> 6, lane = tid & 63;
    const int wrow = wave / WCOLS, wcol = wave % WCOLS;
    const int bm = blockIdx.y * BM, bn = blockIdx.x * BN;
    const int lm = lane & 15, lq = lane >> 4;

    ffrag acc[SM][SN];
#pragma unroll
    for (int i = 0; i < SM; ++i)
#pragma unroll
        for (int j = 0; j < SN; ++j) acc[i][j] = (ffrag){0.f, 0.f, 0.f, 0.f};

    const ushort_t* gptr[IPW];
    int loff[IPW];
#pragma unroll
    for (int e = 0; e < IPW; ++e) {
        int g = wave * IPW + e;
        int s = g >> 1, h = g & 1;
        if (s < NSUBA) {
            int m = bm + s * 16 + lm;
            gptr[e] = A + (long long)(m / agrp) * astride
                        + (long long)(m % agrp) * K + h * 32 + lq * 8;
        } else {
            int n = bn + (s - NSUBA) * 16 + lm;
            gptr[e] = Bt + (long long)n * K + h * 32 + lq * 8;
        }
        loff[e] = s * 1024 + h * 512;
    }

#pragma unroll
    for (int e = 0; e < IPW; ++e)
        GLOAD_LDS16(gptr[e], &lds[loff[e]]);

    const int nk = K >> 6;
    for (int kk = 0; kk < nk; ++kk) {
        __syncthreads();
        if (kk + 1 < nk) {
            const int koff = (kk + 1) << 6;
            const int nb = (kk + 1) & 1;
#pragma unroll
            for (int e = 0; e < IPW; ++e)
                GLOAD_LDS16(gptr[e] + koff, &lds[nb * BUFS + loff[e]]);
        }
        const ushort_t* lb = &lds[(kk & 1) * BUFS];
#pragma unroll
        for (int h = 0; h < 2; ++h) {
            bfrag af[SM], bfg[SN];
#pragma unroll
            for (int i = 0; i < SM; ++i)
                af[i] = *(const bfrag*)&lb[(wrow * SM + i) * 1024 + h * 512 + lane * 8];
#pragma unroll
            for (int j = 0; j < SN; ++j)
                bfg[j] = *(const bfrag*)&lb[(NSUBA + wcol * SN + j) * 1024 + h * 512 + lane * 8];
#pragma unroll
            for (int i = 0; i < SM; ++i)
#pragma unroll
                for (int j = 0; j < SN; ++j)
                    acc[i][j] = MFMA16(af[i], bfg[j], acc[i][j]);
        }
    }

    __syncthreads();
    ushort_t* ep = &lds[wave * WM * EST];
#pragma unroll
    for (int i = 0; i < SM; ++i)
#pragma unroll
        for (int j = 0; j < SN; ++j)
#pragma unroll
            for (int r = 0; r < 4; ++r) {
                int row = i * 16 + lq * 4 + r;
                int col = j * 16 + lm;
                float v = acc[i][j][r];
                if (relu) v = fmaxf(v, 0.f);
                ep[row * EST + col] = f2b(v);
            }
    constexpr int CPR = WN / 8;
    constexpr int RPI = 64 / CPR;
    const int lrow = lane / CPR, lcol = (lane % CPR) * 8;
#pragma unroll
    for (int it = 0; it < WM / RPI; ++it) {
        int row = it * RPI + lrow;
        uint4 v = *(const uint4*)&ep[row * EST + lcol];
        long long grow = bm + wrow * WM + row;
        int gcol = bn + wcol * WN + lcol;
        *(uint4*)&C[grow * N + gcol] = v;
    }
}

// ---------------------------------------------------------------------------
__global__ __launch_bounds__(256) void wtrans_k(
    const float* __restrict__ W, ushort_t* __restrict__ Wt, int K, int N)
{
    __shared__ float t[32][33];
    const int bk = blockIdx.y * 32, bn = blockIdx.x * 32;
    const int tx = threadIdx.x & 31, ty = threadIdx.x >> 5;
    for (int i = ty; i < 32; i += 8)
        t[i][tx] = W[(long long)(bk + i) * N + bn + tx];
    __syncthreads();
    for (int i = ty; i < 32; i += 8)
        Wt[(long long)(bn + i) * K + bk + tx] = f2b(t[tx][i]);
}

__global__ __launch_bounds__(256) void cvt_k(
    const float* __restrict__ in, ushort_t* __restrict__ out, long long n)
{
    long long i = ((long long)blockIdx.x * 256 + threadIdx.x) * 8;
    if (i >= n) return;
    float4 a = *(const float4*)(in + i);
    float4 b = *(const float4*)(in + i + 4);
    ushort_t o[8] = {f2b(a.x), f2b(a.y), f2b(a.z), f2b(a.w),
                     f2b(b.x), f2b(b.y), f2b(b.z), f2b(b.w)};
    *(uint4*)(out + i) = *(const uint4*)o;
}

// ---------------------------------------------------------------------------
// Phase-1 MFMA attention, one (sequence n, head h) per block. S=50->64, D=64.
// ---------------------------------------------------------------------------
__global__ __launch_bounds__(256) void attn_mfma_k(
    const ushort_t* __restrict__ Q, long long qns, long long qrs,
    const ushort_t* __restrict__ K, const ushort_t* __restrict__ V,
    long long kns, long long kvrs,
    ushort_t* __restrict__ O,
    const int* __restrict__ lens, int G, int t0)
{
    __shared__ ushort_t qs[64][72];   // Q, then P
    __shared__ ushort_t ks[64][72];
    __shared__ ushort_t vt[64][72];   // V^T
    const int n = blockIdx.x >> 3, h = blockIdx.x & 7;
    const int tid = threadIdx.x;
    const int wave = tid >> 6, lane = tid & 63;
    const int lm = lane & 15, lq = lane >> 4;
    int len = SEGL;
    if (lens) {
        int b = n / G, t = t0 + (n % G);
        len = lens[b * NT + t];
        if (len > SEGL) len = SEGL;
    }
    {
        uint4 z = {0, 0, 0, 0};
        uint4* vz = (uint4*)&vt[0][0];
        for (int i = tid; i < 64 * 72 / 8; i += 256) vz[i] = z;
    }
    __syncthreads();
    for (int idx = tid; idx < SEGL * 8; idx += 256) {
        int s = idx >> 3, d8 = (idx & 7) << 3;
        const ushort_t* qp = Q + (long long)n * qns + (long long)s * qrs + h * DHEAD + d8;
        const ushort_t* kp = K + (long long)n * kns + (long long)s * kvrs + h * DHEAD + d8;
        const ushort_t* vp = V + (long long)n * kns + (long long)s * kvrs + h * DHEAD + d8;
        *(uint4*)&qs[s][d8] = *(const uint4*)qp;
        *(uint4*)&ks[s][d8] = *(const uint4*)kp;
        uint4 v4 = *(const uint4*)vp;
        const ushort_t* vv = (const ushort_t*)&v4;
#pragma unroll
        for (int u = 0; u < 8; ++u) vt[d8 + u][s] = vv[u];
    }
    __syncthreads();

    ffrag sc[4];
#pragma unroll
    for (int nt = 0; nt < 4; ++nt) sc[nt] = (ffrag){0.f, 0.f, 0.f, 0.f};
#pragma unroll
    for (int kt = 0; kt < 2; ++kt) {
        bfrag a = *(const bfrag*)&qs[wave * 16 + lm][kt * 32 + lq * 8];
#pragma unroll
        for (int nt = 0; nt < 4; ++nt) {
            bfrag b = *(const bfrag*)&ks[nt * 16 + lm][kt * 32 + lq * 8];
            sc[nt] = MFMA16(a, b, sc[nt]);
        }
    }
    __syncthreads();

#pragma unroll
    for (int r = 0; r < 4; ++r) {
        float x[4];
        float mx = -1e30f;
#pragma unroll
        for (int nt = 0; nt < 4; ++nt) {
            int col = nt * 16 + lm;
            x[nt] = (col < len) ? sc[nt][r] * 0.125f : -1e9f;
            mx = fmaxf(mx, x[nt]);
        }
        for (int off = 8; off; off >>= 1) mx = fmaxf(mx, __shfl_xor(mx, off));
        float e[4], se = 0.f;
#pragma unroll
        for (int nt = 0; nt < 4; ++nt) { e[nt] = __expf(x[nt] - mx); se += e[nt]; }
        for (int off = 8; off; off >>= 1) se += __shfl_xor(se, off);
        float inv = 1.f / se;
        int row = wave * 16 + lq * 4 + r;
#pragma unroll
        for (int nt = 0; nt < 4; ++nt)
            qs[row][nt * 16 + lm] = f2b(e[nt] * inv);
    }
    __syncthreads();

    ffrag oc[4];
#pragma unroll
    for (int dt = 0; dt < 4; ++dt) oc[dt] = (ffrag){0.f, 0.f, 0.f, 0.f};
#pragma unroll
    for (int kt = 0; kt < 2; ++kt) {
        bfrag a = *(const bfrag*)&qs[wave * 16 + lm][kt * 32 + lq * 8];
#pragma unroll
        for (int dt = 0; dt < 4; ++dt) {
            bfrag b = *(const bfrag*)&vt[dt * 16 + lm][kt * 32 + lq * 8];
            oc[dt] = MFMA16(a, b, oc[dt]);
        }
    }
#pragma unroll
    for (int r = 0; r < 4; ++r) {
        int i = wave * 16 + lq * 4 + r;
        if (i < SEGL) {
            ushort_t* op = O + (long long)(n * SEGL + i) * DMODEL + h * DHEAD + lm;
#pragma unroll
            for (int dt = 0; dt < 4; ++dt)
                op[dt * 16] = f2b(oc[dt][r]);
        }
    }
}

// ---------------------------------------------------------------------------
// out = LN(a + b)*gamma + beta, rows of 512, bf16 in, bf16/fp32 out. (phase 1)
// ---------------------------------------------------------------------------
template<bool OUTF32>
__global__ __launch_bounds__(256) void add_ln_k(
    const ushort_t* __restrict__ A, int agrp, long long astride,
    const ushort_t* __restrict__ Bv,
    const float* __restrict__ gamma, const float* __restrict__ beta,
    void* __restrict__ O, int ogrp, long long ostride, int M)
{
    const int wave = threadIdx.x >> 6, lane = threadIdx.x & 63;
    const int r = blockIdx.x * 4 + wave;
    if (r >= M) return;
    const ushort_t* a = A + (long long)(r / agrp) * astride + (long long)(r % agrp) * DMODEL;
    const ushort_t* b = Bv + (long long)r * DMODEL;
    float x[8];
    {
        uint4 a4 = *(const uint4*)(a + lane * 8);
        uint4 b4 = *(const uint4*)(b + lane * 8);
        const unsigned* aa = (const unsigned*)&a4;
        const unsigned* bb = (const unsigned*)&b4;
#pragma unroll
        for (int c = 0; c < 4; ++c) {
            union { unsigned u; float f; } alo, ahi, blo, bhi;
            alo.u = aa[c] << 16; ahi.u = aa[c] & 0xffff0000u;
            blo.u = bb[c] << 16; bhi.u = bb[c] & 0xffff0000u;
            x[2 * c]     = alo.f + blo.f;
            x[2 * c + 1] = ahi.f + bhi.f;
        }
    }
    float s = 0.f, s2 = 0.f;
#pragma unroll
    for (int i = 0; i < 8; ++i) { s += x[i]; s2 = fmaf(x[i], x[i], s2); }
    for (int off = 32; off; off >>= 1) {
        s += __shfl_xor(s, off);
        s2 += __shfl_xor(s2, off);
    }
    const float mean = s * (1.f / DMODEL);
    const float var = s2 * (1.f / DMODEL) - mean * mean;
    const float inv = rsqrtf(var + 1e-5f);
    float4 g0 = *(const float4*)(gamma + lane * 8);
    float4 g1 = *(const float4*)(gamma + lane * 8 + 4);
    float4 be0 = *(const float4*)(beta + lane * 8);
    float4 be1 = *(const float4*)(beta + lane * 8 + 4);
    float y[8];
    y[0] = (x[0] - mean) * inv * g0.x + be0.x;
    y[1] = (x[1] - mean) * inv * g0.y + be0.y;
    y[2] = (x[2] - mean) * inv * g0.z + be0.z;
    y[3] = (x[3] - mean) * inv * g0.w + be0.w;
    y[4] = (x[4] - mean) * inv * g1.x + be1.x;
    y[5] = (x[5] - mean) * inv * g1.y + be1.y;
    y[6] = (x[6] - mean) * inv * g1.z + be1.z;
    y[7] = (x[7] - mean) * inv * g1.w + be1.w;
    if (OUTF32) {
        float* o = (float*)O + (long long)(r / ogrp) * ostride + (long long)(r % ogrp) * DMODEL;
        *(float4*)(o + lane * 8) = *(float4*)&y[0];
        *(float4*)(o + lane * 8 + 4) = *(float4*)&y[4];
    } else {
        ushort_t* o = (ushort_t*)O + (long long)(r / ogrp) * ostride + (long long)(r % ogrp) * DMODEL;
        ushort_t ob[8];
#pragma unroll
        for (int i = 0; i < 8; ++i) ob[i] = f2b(y[i]);
        *(uint4*)(o + lane * 8) = *(const uint4*)ob;
    }
}

__global__ void lens_k(const int* __restrict__ ends, int* __restrict__ lens)
{
    int i = blockIdx.x * 256 + threadIdx.x;
    if (i >= NB * NT) return;
    int t = i & (NT - 1);
    int prev = t ? ends[i - 1] : 0;
    int l = ends[i] - prev;
    if (l > SEGL) l = SEGL;
    lens[i] = l;
}

// ===========================================================================
// Phase 2: one block per sequence, 1024 threads (16 waves), all 15 steps.
// Recurrent state P (50x512, padded [64][520]) lives in LDS. Per-block global
// scratch (block-private -> L2): Kg[64][512], VTg[512][64], Sg[8][64][64],
// ATg[64][512], Hg[64][512].
// __launch_bounds__(1024, 4): 4 waves/EU = exactly one block/CU -> VGPR cap
// 128 (round 12's default gave 64 VGPR -> accumulator spills to scratch).
// ===========================================================================
__global__ __launch_bounds__(1024, 4) void phase2_seq(
    const ushort_t* __restrict__ ENC, const ushort_t* __restrict__ QALL,
    const ushort_t* __restrict__ Wkv, const ushort_t* __restrict__ WoT,
    const ushort_t* __restrict__ F1T, const ushort_t* __restrict__ F2T,
    const float* __restrict__ G1v, const float* __restrict__ B1v,
    const float* __restrict__ G2v, const float* __restrict__ B2v,
    ushort_t* __restrict__ SCR, float* __restrict__ out)
{
    extern __shared__ ushort_t lds[];
    ushort_t* Pb = lds;                  // [64][520], stride 1040B (16B-aligned)
    ushort_t* Mb = lds + 64 * 520;       // [64][264], stride 528B
    const int n = blockIdx.x;
    const int tid = threadIdx.x;
    const int w = tid >> 6, lane = tid & 63;
    const int lm = lane & 15, lq = lane >> 4;
    const int hh = w >> 1, wp = w & 1;   // head / wave-pair for attn phases

    ushort_t* Kg  = SCR + (long long)n * 163840;
    ushort_t* VTg = Kg + 32768;
    ushort_t* Sg  = Kg + 65536;
    ushort_t* ATg = Kg + 98304;
    ushort_t* Hg  = Kg + 131072;

    // init P: zero whole buffer (pads stay 0 forever), then rows 0-49 = ENC[n][0]
    {
        uint4 z = {0, 0, 0, 0};
        for (int i = tid; i < 64 * 520 / 8; i += 1024) ((uint4*)Pb)[i] = z;
    }
    __syncthreads();
    for (int idx = tid; idx < 50 * 64; idx += 1024) {
        int s = idx >> 6, c8 = (idx & 63) << 3;
        *(uint4*)&Pb[s * 520 + c8] =
            *(const uint4*)(ENC + (long long)n * 409600 + (long long)s * 512 + c8);
    }
    __syncthreads();

#pragma unroll 1
    for (int t = 1; t < NT; ++t) {
        const ushort_t* Qb = QALL + (long long)n * 384000 + (long long)(t - 1) * 25600;

        // ---- A1: K,V projection. C[64][512] each; A = P (LDS), B = Wkv rows.
        {
            ffrag ka[4][2], va[4][2];
#pragma unroll
            for (int i = 0; i < 4; ++i)
#pragma unroll
                for (int j = 0; j < 2; ++j) {
                    ka[i][j] = (ffrag){0.f, 0.f, 0.f, 0.f};
                    va[i][j] = (ffrag){0.f, 0.f, 0.f, 0.f};
                }
            const ushort_t* wk = Wkv + (long long)(w * 32) * 512;
            const ushort_t* wv = Wkv + (long long)(512 + w * 32) * 512;
#pragma unroll
            for (int k8 = 0; k8 < 16; ++k8) {
                bfrag af[4];
#pragma unroll
                for (int i = 0; i < 4; ++i)
                    af[i] = *(const bfrag*)&Pb[(i * 16 + lm) * 520 + k8 * 32 + lq * 8];
#pragma unroll
                for (int j = 0; j < 2; ++j) {
                    bfrag bk = *(const bfrag*)(wk + (long long)(j * 16 + lm) * 512 + k8 * 32 + lq * 8);
                    bfrag bv = *(const bfrag*)(wv + (long long)(j * 16 + lm) * 512 + k8 * 32 + lq * 8);
#pragma unroll
                    for (int i = 0; i < 4; ++i) {
                        ka[i][j] = MFMA16(af[i], bk, ka[i][j]);
                        va[i][j] = MFMA16(af[i], bv, va[i][j]);
                    }
                }
            }
#pragma unroll
            for (int i = 0; i < 4; ++i)
#pragma unroll
                for (int j = 0; j < 2; ++j)
#pragma unroll
                    for (int r = 0; r < 4; ++r) {
                        int row = i * 16 + lq * 4 + r;
                        int col = w * 32 + j * 16 + lm;
                        Kg[row * 512 + col] = f2b(ka[i][j][r]);
                        VTg[col * 64 + row] = f2b(va[i][j][r]);
                    }
        }
        __syncthreads();

        // ---- A2: QK^T + softmax for head hh (2 waves/head). S -> Sg[hh].
        {
            ffrag sc[2][4];
#pragma unroll
            for (int i = 0; i < 2; ++i)
#pragma unroll
                for (int j = 0; j < 4; ++j) sc[i][j] = (ffrag){0.f, 0.f, 0.f, 0.f};
#pragma unroll
            for (int kk = 0; kk < 2; ++kk) {
                bfrag aq[2];
#pragma unroll
                for (int ii = 0; ii < 2; ++ii)
                    aq[ii] = *(const bfrag*)(Qb + (long long)((wp * 2 + ii) * 16 + lm) * 512
                                             + hh * 64 + kk * 32 + lq * 8);
#pragma unroll
                for (int j = 0; j < 4; ++j) {
                    bfrag bk = *(const bfrag*)&Kg[(j * 16 + lm) * 512 + hh * 64 + kk * 32 + lq * 8];
#pragma unroll
                    for (int ii = 0; ii < 2; ++ii)
                        sc[ii][j] = MFMA16(aq[ii], bk, sc[ii][j]);
                }
            }
#pragma unroll
            for (int ii = 0; ii < 2; ++ii)
#pragma unroll
                for (int r = 0; r < 4; ++r) {
                    float x[4], mx = -1e30f;
#pragma unroll
                    for (int j = 0; j < 4; ++j) {
                        int col = j * 16 + lm;
                        x[j] = (col < SEGL) ? sc[ii][j][r] * 0.125f : -1e9f;
                        mx = fmaxf(mx, x[j]);
                    }
                    for (int off = 8; off; off >>= 1) mx = fmaxf(mx, __shfl_xor(mx, off));
                    float e[4], se = 0.f;
#pragma unroll
                    for (int j = 0; j < 4; ++j) { e[j] = __expf(x[j] - mx); se += e[j]; }
                    for (int off = 8; off; off >>= 1) se += __shfl_xor(se, off);
                    float inv = 1.f / se;
                    int row = (wp * 2 + ii) * 16 + lq * 4 + r;
#pragma unroll
                    for (int j = 0; j < 4; ++j)
                        Sg[hh * 4096 + row * 64 + j * 16 + lm] = f2b(e[j] * inv);
                }
        }
        __syncthreads();

        // ---- A3: PV for head hh. attn[:, hh*64..] -> ATg.
        {
            ffrag oc[2][4];
#pragma unroll
            for (int i = 0; i < 2; ++i)
#pragma unroll
                for (int j = 0; j < 4; ++j) oc[i][j] = (ffrag){0.f, 0.f, 0.f, 0.f};
#pragma unroll
            for (int kk = 0; kk < 2; ++kk) {
                bfrag as[2];
#pragma unroll
                for (int ii = 0; ii < 2; ++ii)
                    as[ii] = *(const bfrag*)&Sg[hh * 4096 + ((wp * 2 + ii) * 16 + lm) * 64
                                                + kk * 32 + lq * 8];
#pragma unroll
                for (int j = 0; j < 4; ++j) {
                    bfrag bv = *(const bfrag*)&VTg[(hh * 64 + j * 16 + lm) * 64 + kk * 32 + lq * 8];
#pragma unroll
                    for (int ii = 0; ii < 2; ++ii)
                        oc[ii][j] = MFMA16(as[ii], bv, oc[ii][j]);
                }
            }
#pragma unroll
            for (int ii = 0; ii < 2; ++ii)
#pragma unroll
                for (int j = 0; j < 4; ++j)
#pragma unroll
                    for (int r = 0; r < 4; ++r) {
                        int row = (wp * 2 + ii) * 16 + lq * 4 + r;
                        int col = hh * 64 + j * 16 + lm;
                        ATg[row * 512 + col] = f2b(oc[ii][j][r]);
                    }
        }
        __syncthreads();

        // ---- B: Wo GEMM. Hg = ATg @ WoT^T. N-strip 32/wave, K=512.
        {
            ffrag acc[4][2];
#pragma unroll
            for (int i = 0; i < 4; ++i)
#pragma unroll
                for (int j = 0; j < 2; ++j) acc[i][j] = (ffrag){0.f, 0.f, 0.f, 0.f};
#pragma unroll
            for (int k8 = 0; k8 < 16; ++k8) {
                bfrag af[4];
#pragma unroll
                for (int i = 0; i < 4; ++i)
                    af[i] = *(const bfrag*)&ATg[(i * 16 + lm) * 512 + k8 * 32 + lq * 8];
#pragma unroll
                for (int j = 0; j < 2; ++j) {
                    bfrag bw = *(const bfrag*)(WoT + (long long)(w * 32 + j * 16 + lm) * 512
                                               + k8 * 32 + lq * 8);
#pragma unroll
                    for (int i = 0; i < 4; ++i)
                        acc[i][j] = MFMA16(af[i], bw, acc[i][j]);
                }
            }
#pragma unroll
            for (int i = 0; i < 4; ++i)
#pragma unroll
                for (int j = 0; j < 2; ++j)
#pragma unroll
                    for (int r = 0; r < 4; ++r)
                        Hg[(i * 16 + lq * 4 + r) * 512 + w * 32 + j * 16 + lm] = f2b(acc[i][j][r]);
        }
        __syncthreads();

        // ---- C: LN1 in place: Hg = LN(curr + Hg), rows 0-49.
        for (int r = w; r < SEGL; r += 16) {
            const ushort_t* cr = ENC + (long long)n * 409600 + (long long)(t * 50 + r) * 512;
            uint4 a4 = *(const uint4*)&Hg[r * 512 + lane * 8];
            uint4 b4 = *(const uint4*)(cr + lane * 8);
            const unsigned* aa = (const unsigned*)&a4;
            const unsigned* bb = (const unsigned*)&b4;
            float x[8];
#pragma unroll
            for (int c = 0; c < 4; ++c) {
                union { unsigned u; float f; } alo, ahi, blo, bhi;
                alo.u = aa[c] << 16; ahi.u = aa[c] & 0xffff0000u;
                blo.u = bb[c] << 16; bhi.u = bb[c] & 0xffff0000u;
                x[2 * c]     = alo.f + blo.f;
                x[2 * c + 1] = ahi.f + bhi.f;
            }
            float s = 0.f, s2 = 0.f;
#pragma unroll
            for (int i = 0; i < 8; ++i) { s += x[i]; s2 = fmaf(x[i], x[i], s2); }
            for (int off = 32; off; off >>= 1) { s += __shfl_xor(s, off); s2 += __shfl_xor(s2, off); }
            float mean = s * (1.f / DMODEL);
            float var = s2 * (1.f / DMODEL) - mean * mean;
            float inv = rsqrtf(var + 1e-5f);
            float4 g0 = *(const float4*)(G1v + lane * 8);
            float4 g1 = *(const float4*)(G1v + lane * 8 + 4);
            float4 e0 = *(const float4*)(B1v + lane * 8);
            float4 e1 = *(const float4*)(B1v + lane * 8 + 4);
            ushort_t ob[8];
            ob[0] = f2b((x[0] - mean) * inv * g0.x + e0.x);
            ob[1] = f2b((x[1] - mean) * inv * g0.y + e0.y);
            ob[2] = f2b((x[2] - mean) * inv * g0.z + e0.z);
            ob[3] = f2b((x[3] - mean) * inv * g0.w + e0.w);
            ob[4] = f2b((x[4] - mean) * inv * g1.x + e1.x);
            ob[5] = f2b((x[5] - mean) * inv * g1.y + e1.y);
            ob[6] = f2b((x[6] - mean) * inv * g1.z + e1.z);
            ob[7] = f2b((x[7] - mean) * inv * g1.w + e1.w);
            *(uint4*)&Hg[r * 512 + lane * 8] = *(const uint4*)ob;
        }
        __syncthreads();

        // ---- D: FFN. 8 chunks of 256 ff-cols; F1 -> Mb (LDS) -> F2 acc in regs.
        ffrag fa[4][2];
#pragma unroll
        for (int i = 0; i < 4; ++i)
#pragma unroll
            for (int j = 0; j < 2; ++j) fa[i][j] = (ffrag){0.f, 0.f, 0.f, 0.f};
#pragma unroll 1
        for (int cc = 0; cc < 8; ++cc) {
            ffrag m1[4];
#pragma unroll
            for (int i = 0; i < 4; ++i) m1[i] = (ffrag){0.f, 0.f, 0.f, 0.f};
#pragma unroll
            for (int k8 = 0; k8 < 16; ++k8) {
                bfrag ah[4];
#pragma unroll
                for (int i = 0; i < 4; ++i)
                    ah[i] = *(const bfrag*)&Hg[(i * 16 + lm) * 512 + k8 * 32 + lq * 8];
                bfrag b1 = *(const bfrag*)(F1T + (long long)(cc * 256 + w * 16 + lm) * 512
                                           + k8 * 32 + lq * 8);
#pragma unroll
                for (int i = 0; i < 4; ++i) m1[i] = MFMA16(ah[i], b1, m1[i]);
            }
            __syncthreads();   // prior chunk's F2 reads of Mb done
#pragma unroll
            for (int i = 0; i < 4; ++i)
#pragma unroll
                for (int r = 0; r < 4; ++r)
                    Mb[(i * 16 + lq * 4 + r) * 264 + w * 16 + lm] = f2b(fmaxf(m1[i][r], 0.f));
            __syncthreads();
#pragma unroll
            for (int k8 = 0; k8 < 8; ++k8) {
                bfrag am[4];
#pragma unroll
                for (int i = 0; i < 4; ++i)
                    am[i] = *(const bfrag*)&Mb[(i * 16 + lm) * 264 + k8 * 32 + lq * 8];
#pragma unroll
                for (int j = 0; j < 2; ++j) {
                    bfrag b2 = *(const bfrag*)(F2T + (long long)(w * 32 + j * 16 + lm) * 2048
                                               + cc * 256 + k8 * 32 + lq * 8);
#pragma unroll
                    for (int i = 0; i < 4; ++i) fa[i][j] = MFMA16(am[i], b2, fa[i][j]);
                }
            }
        }
        // write ffn result to ATg (dead since Wo)
#pragma unroll
        for (int i = 0; i < 4; ++i)
#pragma unroll
            for (int j = 0; j < 2; ++j)
#pragma unroll
                for (int r = 0; r < 4; ++r)
                    ATg[(i * 16 + lq * 4 + r) * 512 + w * 32 + j * 16 + lm] = f2b(fa[i][j][r]);
        __syncthreads();

        // ---- E: LN2 -> P (LDS) rows 0-49; f32 out on last step.
        for (int r = w; r < SEGL; r += 16) {
            uint4 a4 = *(const uint4*)&Hg[r * 512 + lane * 8];
            uint4 b4 = *(const uint4*)&ATg[r * 512 + lane * 8];
            const unsigned* aa = (const unsigned*)&a4;
            const unsigned* bb = (const unsigned*)&b4;
            float x[8];
#pragma unroll
            for (int c = 0; c < 4; ++c) {
                union { unsigned u; float f; } alo, ahi, blo, bhi;
                alo.u = aa[c] << 16; ahi.u = aa[c] & 0xffff0000u;
                blo.u = bb[c] << 16; bhi.u = bb[c] & 0xffff0000u;
                x[2 * c]     = alo.f + blo.f;
                x[2 * c + 1] = ahi.f + bhi.f;
            }
            float s = 0.f, s2 = 0.f;
#pragma unroll
            for (int i = 0; i < 8; ++i) { s += x[i]; s2 = fmaf(x[i], x[i], s2); }
            for (int off = 32; off; off >>= 1) { s += __shfl_xor(s, off); s2 += __shfl_xor(s2, off); }
            float mean = s * (1.f / DMODEL);
            float var = s2 * (1.f / DMODEL) - mean * mean;
            float inv = rsqrtf(var + 1e-5f);
            float4 g0 = *(const float4*)(G2v + lane * 8);
            float4 g1 = *(const float4*)(G2v + lane * 8 + 4);
            float4 e0 = *(const float4*)(B2v + lane * 8);
            float4 e1 = *(const float4*)(B2v + lane * 8 + 4);
            float y[8];
            y[0] = (x[0] - mean) * inv * g0.x + e0.x;
            y[1] = (x[1] - mean) * inv * g0.y + e0.y;
            y[2] = (x[2] - mean) * inv * g0.z + e0.z;
            y[3] = (x[3] - mean) * inv * g0.w + e0.w;
            y[4] = (x[4] - mean) * inv * g1.x + e1.x;
            y[5] = (x[5] - mean) * inv * g1.y + e1.y;
            y[6] = (x[6] - mean) * inv * g1.z + e1.z;
            y[7] = (x[7] - mean) * inv * g1.w + e1.w;
            if (t == NT - 1) {
                float* o = out + ((long long)n * 50 + r) * 512 + lane * 8;
                *(float4*)o = *(float4*)&y[0];
                *(float4*)(o + 4) = *(float4*)&y[4];
            } else {
                ushort_t ob[8];
#pragma unroll
                for (int i = 0; i < 8; ++i) ob[i] = f2b(y[i]);
                *(uint4*)&Pb[r * 520 + lane * 8] = *(const uint4*)ob;
            }
        }
        __syncthreads();
    }
}

// ---------------------------------------------------------------------------
extern "C" void kernel_launch(void* const* d_in, const int* in_sizes, int n_in,
                              void* d_out, int out_size, void* d_ws, size_t ws_size,
                              hipStream_t stream)
{
    const float* seqs = (const float*)d_in[0];
    const int*   ends = (const int*)d_in[1];
    const float* eG1 = (const float*)d_in[7],  *eB1 = (const float*)d_in[8];
    const float* eG2 = (const float*)d_in[11], *eB2 = (const float*)d_in[12];
    const float* cG1 = (const float*)d_in[17], *cB1 = (const float*)d_in[18];
    const float* cG2 = (const float*)d_in[21], *cB2 = (const float*)d_in[22];
    float* out = (float*)d_out;

    const int G = (ws_size >= (size_t)470000000) ? 8 : 4;
    const long long CH = 1638400LL * G;

    ushort_t* ws = (ushort_t*)d_ws;
    const long long SEQROW = (long long)NT * SEGL * DMODEL;    // 409600
    ushort_t* SEQB = ws;
    ushort_t* WT   = SEQB + 26214400LL;
    ushort_t* ENC  = WT   + 6553600LL;
    ushort_t* BUF0 = ENC  + 26214400LL;
    ushort_t* QKV  = BUF0 + CH;
    ushort_t* BUF4 = QKV  + 3 * CH;
    ushort_t* BUF1 = BUF4 + CH;
    ushort_t* BUF2 = BUF1 + CH;
    ushort_t* MID  = BUF2 + CH;
    ushort_t* OUTB = MID  + 4 * CH;
    ushort_t* QALL = OUTB + 1638400LL;
    int*      lens = (int*)(QALL + 24576000LL);

    const ushort_t* eWinT = WT + 0;
    const ushort_t* WQKVe = WT + 262144;      // 1536 x 512
    const ushort_t* eWoT  = WT + 1048576;
    const ushort_t* eF1T  = WT + 1310720;     // 2048 x 512
    const ushort_t* eF2T  = WT + 2359296;     // 512 x 2048
    const ushort_t* cWqT  = WT + 3407872;
    const ushort_t* cKV   = WT + 3670016;     // 1024 x 512 (cWk^T | cWv^T)
    const ushort_t* cWoT  = WT + 4194304;
    const ushort_t* cF1T  = WT + 4456448;
    const ushort_t* cF2T  = WT + 5505024;

    struct WMap { int src; long long dst; int K, N; };
    const WMap wm[13] = {
        {2,  0,       512, 512},
        {3,  262144,  512, 512},
        {4,  524288,  512, 512},
        {5,  786432,  512, 512},
        {6,  1048576, 512, 512},
        {9,  1310720, 512, 2048},
        {10, 2359296, 2048, 512},
        {13, 3407872, 512, 512},
        {14, 3670016, 512, 512},
        {15, 3932160, 512, 512},
        {16, 4194304, 512, 512},
        {19, 4456448, 512, 2048},
        {20, 5505024, 2048, 512},
    };

    cvt_k<<<12800, 256, 0, stream>>>(seqs, SEQB, 26214400LL);
    for (int w = 0; w < 13; ++w) {
        dim3 g(wm[w].N / 32, wm[w].K / 32);
        wtrans_k<<<g, 256, 0, stream>>>((const float*)d_in[wm[w].src],
                                        WT + wm[w].dst, wm[w].K, wm[w].N);
    }
    lens_k<<<4, 256, 0, stream>>>(ends, lens);

    auto gemmL = [&](const ushort_t* A, int agrp, long long astr, const ushort_t* Bt,
                     ushort_t* C, int M, int N, int K, int relu) {
        dim3 g(N / 128, M / 128);
        mfma_gemm<128, 128, 2, 2><<<g, 256, 0, stream>>>(A, agrp, astr, Bt, C, M, N, K, relu);
    };

    // ---------------- Phase 1: all encoders, chunks of G segments ----------
    const int Mc = NB * G * SEGL;
    for (int c = 0; c < NT / G; ++c) {
        const int t0 = c * G;
        const ushort_t* Abase = SEQB + (long long)t0 * SEGL * DMODEL;
        ushort_t* ENCc = ENC + (long long)t0 * SEGL * DMODEL;
        gemmL(Abase, G * SEGL, SEQROW, eWinT, BUF0, Mc, 512, 512, 0);
        gemmL(BUF0, Mc, 0, WQKVe, QKV, Mc, 1536, 512, 0);
        attn_mfma_k<<<NB * G * NHEAD, 256, 0, stream>>>(
            QKV, 50LL * 1536, 1536, QKV + 512, QKV + 1024, 50LL * 1536, 1536,
            BUF4, lens, G, t0);
        gemmL(BUF4, Mc, 0, eWoT, BUF1, Mc, 512, 512, 0);
        add_ln_k<false><<<Mc / 4, 256, 0, stream>>>(BUF0, Mc, 0, BUF1, eG1, eB1,
                                                    BUF2, Mc, 0, Mc);
        gemmL(BUF2, Mc, 0, eF1T, MID, Mc, 2048, 512, 1);
        gemmL(MID, Mc, 0, eF2T, BUF1, Mc, 512, 2048, 0);
        add_ln_k<false><<<Mc / 4, 256, 0, stream>>>(BUF2, Mc, 0, BUF1, eG2, eB2,
                                                    ENCc, G * SEGL, SEQROW, Mc);
    }

    // Batched Q projections for ALL phase-2 steps
    gemmL(ENC + 25600, 750, SEQROW, cWqT, QALL, 48000, 512, 512, 0);

    // ---------------- Phase 2: 64 independent per-sequence chains ----------
    {
        constexpr int LDS_BYTES = (64 * 520 + 64 * 264) * 2;   // 100352
        static bool attr_set = false;
        if (!attr_set) {
            hipFuncSetAttribute((const void*)phase2_seq,
                                hipFuncAttributeMaxDynamicSharedMemorySize,
                                LDS_BYTES);
            attr_set = true;
        }
        phase2_seq<<<64, 1024, LDS_BYTES, stream>>>(
            ENC, QALL, cKV, cWoT, cF1T, cF2T,
            cG1, cB1, cG2, cB2, MID, out);
    }
}

// Round 6
// 3754.238 us; speedup vs baseline: 2.8838x; 2.8838x over previous
//
#include <hip/hip_runtime.h>

// RecurrentTransformerEncoder on MI355X — round 14: revert to the verified
// round-8 multi-launch phase 2 (persistent/per-seq experiments of rounds 9-13
// all lost to grid-barrier fences or unhidden weight-load latency), and fuse
// the two add+LN kernels into their preceding GEMMs: new gemm_ln_k = proven
// mfma_gemm BK=64 gload-dbuf K-loop (BM=64 x full N=512, 8 waves) + proven
// add_ln epilogue via LDS. 6 -> 4 launches/step.
// B=64, T=16, SEG=50, E=D=512, H=8, DH=64, F=2048.

#define NB   64
#define NT   16
#define SEGL 50
#define DMODEL 512
#define DFF  2048
#define NHEAD 8
#define DHEAD 64

typedef unsigned short ushort_t;
typedef __attribute__((ext_vector_type(8))) short bfrag;   // 8 bf16 (4 VGPRs)
typedef __attribute__((ext_vector_type(4))) float ffrag;   // 4 fp32 acc

__device__ __forceinline__ ushort_t f2b(float x) {
    union { float f; unsigned u; } c; c.f = x;
    unsigned r = c.u + 0x7fffu + ((c.u >> 16) & 1u);
    return (ushort_t)(r >> 16);
}

#define GLOAD_LDS16(g, l) __builtin_amdgcn_global_load_lds( \
    (const __attribute__((address_space(1))) void*)(g),      \
    (__attribute__((address_space(3))) void*)(l), 16, 0, 0)

#define MFMA16(a, b, c) __builtin_amdgcn_mfma_f32_16x16x32_bf16(a, b, c, 0, 0, 0)

// ---------------------------------------------------------------------------
// MFMA GEMM (LDS-staged, BK=64 dbuf): C = relu?(A @ Bt^T), bf16.
// A rows remapped: row m at A + (m/agrp)*astride + (m%agrp)*K.
// ---------------------------------------------------------------------------
template<int BM, int BN, int WROWS, int WCOLS>
__global__ __launch_bounds__(256) void mfma_gemm(
    const ushort_t* __restrict__ A, int agrp, long long astride,
    const ushort_t* __restrict__ Bt, ushort_t* __restrict__ C,
    int M, int N, int K, int relu)
{
    constexpr int WM = BM / WROWS, WN = BN / WCOLS;
    constexpr int SM = WM / 16, SN = WN / 16;
    constexpr int NSUBA = BM / 16, NSUBB = BN / 16;
    constexpr int NSUB = NSUBA + NSUBB;
    constexpr int NINST = NSUB * 2;
    constexpr int IPW = NINST / 4;
    constexpr int BUFS = NSUB * 1024;
    constexpr int EST = WN + 8;
    constexpr int LDS_KLOOP = 2 * BUFS;
    constexpr int LDS_EPI   = 4 * WM * EST;
    constexpr int LDS_SZ = LDS_KLOOP > LDS_EPI ? LDS_KLOOP : LDS_EPI;
    __shared__ ushort_t lds[LDS_SZ];

    const int tid = threadIdx.x;
    const int wave = tid >> 6, lane = tid & 63;
    const int wrow = wave / WCOLS, wcol = wave % WCOLS;
    const int bm = blockIdx.y * BM, bn = blockIdx.x * BN;
    const int lm = lane & 15, lq = lane >> 4;

    ffrag acc[SM][SN];
#pragma unroll
    for (int i = 0; i < SM; ++i)
#pragma unroll
        for (int j = 0; j < SN; ++j) acc[i][j] = (ffrag){0.f, 0.f, 0.f, 0.f};

    const ushort_t* gptr[IPW];
    int loff[IPW];
#pragma unroll
    for (int e = 0; e < IPW; ++e) {
        int g = wave * IPW + e;
        int s = g >> 1, h = g & 1;
        if (s < NSUBA) {
            int m = bm + s * 16 + lm;
            gptr[e] = A + (long long)(m / agrp) * astride
                        + (long long)(m % agrp) * K + h * 32 + lq * 8;
        } else {
            int n = bn + (s - NSUBA) * 16 + lm;
            gptr[e] = Bt + (long long)n * K + h * 32 + lq * 8;
        }
        loff[e] = s * 1024 + h * 512;
    }

#pragma unroll
    for (int e = 0; e < IPW; ++e)
        GLOAD_LDS16(gptr[e], &lds[loff[e]]);

    const int nk = K >> 6;
    for (int kk = 0; kk < nk; ++kk) {
        __syncthreads();
        if (kk + 1 < nk) {
            const int koff = (kk + 1) << 6;
            const int nb = (kk + 1) & 1;
#pragma unroll
            for (int e = 0; e < IPW; ++e)
                GLOAD_LDS16(gptr[e] + koff, &lds[nb * BUFS + loff[e]]);
        }
        const ushort_t* lb = &lds[(kk & 1) * BUFS];
#pragma unroll
        for (int h = 0; h < 2; ++h) {
            bfrag af[SM], bfg[SN];
#pragma unroll
            for (int i = 0; i < SM; ++i)
                af[i] = *(const bfrag*)&lb[(wrow * SM + i) * 1024 + h * 512 + lane * 8];
#pragma unroll
            for (int j = 0; j < SN; ++j)
                bfg[j] = *(const bfrag*)&lb[(NSUBA + wcol * SN + j) * 1024 + h * 512 + lane * 8];
#pragma unroll
            for (int i = 0; i < SM; ++i)
#pragma unroll
                for (int j = 0; j < SN; ++j)
                    acc[i][j] = MFMA16(af[i], bfg[j], acc[i][j]);
        }
    }

    __syncthreads();
    ushort_t* ep = &lds[wave * WM * EST];
#pragma unroll
    for (int i = 0; i < SM; ++i)
#pragma unroll
        for (int j = 0; j < SN; ++j)
#pragma unroll
            for (int r = 0; r < 4; ++r) {
                int row = i * 16 + lq * 4 + r;
                int col = j * 16 + lm;
                float v = acc[i][j][r];
                if (relu) v = fmaxf(v, 0.f);
                ep[row * EST + col] = f2b(v);
            }
    constexpr int CPR = WN / 8;
    constexpr int RPI = 64 / CPR;
    const int lrow = lane / CPR, lcol = (lane % CPR) * 8;
#pragma unroll
    for (int it = 0; it < WM / RPI; ++it) {
        int row = it * RPI + lrow;
        uint4 v = *(const uint4*)&ep[row * EST + lcol];
        long long grow = bm + wrow * WM + row;
        int gcol = bn + wcol * WN + lcol;
        *(uint4*)&C[grow * N + gcol] = v;
    }
}

// ---------------------------------------------------------------------------
// Fused GEMM(BM=64 x N=512) + residual-add + LayerNorm. Grid: M/64 blocks,
// 512 threads (8 waves; wave w owns cols w*64..w*64+63). Same BK=64
// gload-dbuf staging as mfma_gemm (NSUB=36, IPW=9). Epilogue: C -> LDS,
// then add_ln math per row. Dynamic LDS = 2*36864 ushorts = 147456 B.
// ---------------------------------------------------------------------------
template<bool OUTF32>
__global__ __launch_bounds__(512, 2) void gemm_ln_k(
    const ushort_t* __restrict__ A, int agrp, long long astride,
    const ushort_t* __restrict__ Bt, int K,
    const ushort_t* __restrict__ Res, int rgrp, long long rstride,
    const float* __restrict__ gamma, const float* __restrict__ beta,
    void* __restrict__ O)
{
    constexpr int NSUBA = 4, NSUBB = 32, NSUB = 36;
    constexpr int IPW = NSUB * 2 / 8;          // 9
    constexpr int BUFS = NSUB * 1024;          // 36864 ushorts
    extern __shared__ ushort_t lds[];

    const int tid = threadIdx.x;
    const int wave = tid >> 6, lane = tid & 63;
    const int bm = blockIdx.x * 64;
    const int lm = lane & 15, lq = lane >> 4;

    ffrag acc[4][4];
#pragma unroll
    for (int i = 0; i < 4; ++i)
#pragma unroll
        for (int j = 0; j < 4; ++j) acc[i][j] = (ffrag){0.f, 0.f, 0.f, 0.f};

    const ushort_t* gptr[IPW];
    int loff[IPW];
#pragma unroll
    for (int e = 0; e < IPW; ++e) {
        int g = wave * IPW + e;
        int s = g >> 1, h = g & 1;
        if (s < NSUBA) {
            int m = bm + s * 16 + lm;
            gptr[e] = A + (long long)(m / agrp) * astride
                        + (long long)(m % agrp) * K + h * 32 + lq * 8;
        } else {
            int n = (s - NSUBA) * 16 + lm;
            gptr[e] = Bt + (long long)n * K + h * 32 + lq * 8;
        }
        loff[e] = s * 1024 + h * 512;
    }

#pragma unroll
    for (int e = 0; e < IPW; ++e)
        GLOAD_LDS16(gptr[e], &lds[loff[e]]);

    const int nk = K >> 6;
    for (int kk = 0; kk < nk; ++kk) {
        __syncthreads();
        if (kk + 1 < nk) {
            const int koff = (kk + 1) << 6;
            const int nb = (kk + 1) & 1;
#pragma unroll
            for (int e = 0; e < IPW; ++e)
                GLOAD_LDS16(gptr[e] + koff, &lds[nb * BUFS + loff[e]]);
        }
        const ushort_t* lb = &lds[(kk & 1) * BUFS];
#pragma unroll
        for (int h = 0; h < 2; ++h) {
            bfrag af[4], bfg[4];
#pragma unroll
            for (int i = 0; i < 4; ++i)
                af[i] = *(const bfrag*)&lb[i * 1024 + h * 512 + lane * 8];
#pragma unroll
            for (int j = 0; j < 4; ++j)
                bfg[j] = *(const bfrag*)&lb[(NSUBA + wave * 4 + j) * 1024 + h * 512 + lane * 8];
#pragma unroll
            for (int i = 0; i < 4; ++i)
#pragma unroll
                for (int j = 0; j < 4; ++j)
                    acc[i][j] = MFMA16(af[i], bfg[j], acc[i][j]);
        }
    }

    __syncthreads();   // all staging reads done; reuse lds as Cs[64][520]
    ushort_t* Cs = lds;
#pragma unroll
    for (int i = 0; i < 4; ++i)
#pragma unroll
        for (int j = 0; j < 4; ++j)
#pragma unroll
            for (int r = 0; r < 4; ++r) {
                int row = i * 16 + lq * 4 + r;
                int col = wave * 64 + j * 16 + lm;
                Cs[row * 520 + col] = f2b(acc[i][j][r]);
            }
    __syncthreads();

    // LN over all 64 rows (M=3200 is a multiple of 64; every row is data).
    for (int r = wave; r < 64; r += 8) {
        long long rr = bm + r;
        const ushort_t* b = Res + (rr / rgrp) * rstride + (rr % rgrp) * DMODEL;
        uint4 a4 = *(const uint4*)&Cs[r * 520 + lane * 8];
        uint4 b4 = *(const uint4*)(b + lane * 8);
        const unsigned* aa = (const unsigned*)&a4;
        const unsigned* bb = (const unsigned*)&b4;
        float x[8];
#pragma unroll
        for (int c = 0; c < 4; ++c) {
            union { unsigned u; float f; } alo, ahi, blo, bhi;
            alo.u = aa[c] << 16; ahi.u = aa[c] & 0xffff0000u;
            blo.u = bb[c] << 16; bhi.u = bb[c] & 0xffff0000u;
            x[2 * c]     = alo.f + blo.f;
            x[2 * c + 1] = ahi.f + bhi.f;
        }
        float s = 0.f, s2 = 0.f;
#pragma unroll
        for (int i = 0; i < 8; ++i) { s += x[i]; s2 = fmaf(x[i], x[i], s2); }
        for (int off = 32; off; off >>= 1) {
            s += __shfl_xor(s, off);
            s2 += __shfl_xor(s2, off);
        }
        const float mean = s * (1.f / DMODEL);
        const float var = s2 * (1.f / DMODEL) - mean * mean;
        const float inv = rsqrtf(var + 1e-5f);
        float4 g0 = *(const float4*)(gamma + lane * 8);
        float4 g1 = *(const float4*)(gamma + lane * 8 + 4);
        float4 e0 = *(const float4*)(beta + lane * 8);
        float4 e1 = *(const float4*)(beta + lane * 8 + 4);
        float y[8];
        y[0] = (x[0] - mean) * inv * g0.x + e0.x;
        y[1] = (x[1] - mean) * inv * g0.y + e0.y;
        y[2] = (x[2] - mean) * inv * g0.z + e0.z;
        y[3] = (x[3] - mean) * inv * g0.w + e0.w;
        y[4] = (x[4] - mean) * inv * g1.x + e1.x;
        y[5] = (x[5] - mean) * inv * g1.y + e1.y;
        y[6] = (x[6] - mean) * inv * g1.z + e1.z;
        y[7] = (x[7] - mean) * inv * g1.w + e1.w;
        if (OUTF32) {
            float* o = (float*)O + rr * DMODEL + lane * 8;
            *(float4*)o = *(float4*)&y[0];
            *(float4*)(o + 4) = *(float4*)&y[4];
        } else {
            ushort_t* o = (ushort_t*)O + rr * DMODEL + lane * 8;
            ushort_t ob[8];
#pragma unroll
            for (int i = 0; i < 8; ++i) ob[i] = f2b(y[i]);
            *(uint4*)o = *(const uint4*)ob;
        }
    }
}

// ---------------------------------------------------------------------------
__global__ __launch_bounds__(256) void wtrans_k(
    const float* __restrict__ W, ushort_t* __restrict__ Wt, int K, int N)
{
    __shared__ float t[32][33];
    const int bk = blockIdx.y * 32, bn = blockIdx.x * 32;
    const int tx = threadIdx.x & 31, ty = threadIdx.x >> 5;
    for (int i = ty; i < 32; i += 8)
        t[i][tx] = W[(long long)(bk + i) * N + bn + tx];
    __syncthreads();
    for (int i = ty; i < 32; i += 8)
        Wt[(long long)(bn + i) * K + bk + tx] = f2b(t[tx][i]);
}

__global__ __launch_bounds__(256) void cvt_k(
    const float* __restrict__ in, ushort_t* __restrict__ out, long long n)
{
    long long i = ((long long)blockIdx.x * 256 + threadIdx.x) * 8;
    if (i >= n) return;
    float4 a = *(const float4*)(in + i);
    float4 b = *(const float4*)(in + i + 4);
    ushort_t o[8] = {f2b(a.x), f2b(a.y), f2b(a.z), f2b(a.w),
                     f2b(b.x), f2b(b.y), f2b(b.z), f2b(b.w)};
    *(uint4*)(out + i) = *(const uint4*)o;
}

// ---------------------------------------------------------------------------
// Phase-1 MFMA attention, one (sequence n, head h) per block. S=50->64, D=64.
// ---------------------------------------------------------------------------
__global__ __launch_bounds__(256) void attn_mfma_k(
    const ushort_t* __restrict__ Q, long long qns, long long qrs,
    const ushort_t* __restrict__ K, const ushort_t* __restrict__ V,
    long long kns, long long kvrs,
    ushort_t* __restrict__ O,
    const int* __restrict__ lens, int G, int t0)
{
    __shared__ ushort_t qs[64][72];   // Q, then P
    __shared__ ushort_t ks[64][72];
    __shared__ ushort_t vt[64][72];   // V^T
    const int n = blockIdx.x >> 3, h = blockIdx.x & 7;
    const int tid = threadIdx.x;
    const int wave = tid >> 6, lane = tid & 63;
    const int lm = lane & 15, lq = lane >> 4;
    int len = SEGL;
    if (lens) {
        int b = n / G, t = t0 + (n % G);
        len = lens[b * NT + t];
        if (len > SEGL) len = SEGL;
    }
    {
        uint4 z = {0, 0, 0, 0};
        uint4* vz = (uint4*)&vt[0][0];
        for (int i = tid; i < 64 * 72 / 8; i += 256) vz[i] = z;
    }
    __syncthreads();
    for (int idx = tid; idx < SEGL * 8; idx += 256) {
        int s = idx >> 3, d8 = (idx & 7) << 3;
        const ushort_t* qp = Q + (long long)n * qns + (long long)s * qrs + h * DHEAD + d8;
        const ushort_t* kp = K + (long long)n * kns + (long long)s * kvrs + h * DHEAD + d8;
        const ushort_t* vp = V + (long long)n * kns + (long long)s * kvrs + h * DHEAD + d8;
        *(uint4*)&qs[s][d8] = *(const uint4*)qp;
        *(uint4*)&ks[s][d8] = *(const uint4*)kp;
        uint4 v4 = *(const uint4*)vp;
        const ushort_t* vv = (const ushort_t*)&v4;
#pragma unroll
        for (int u = 0; u < 8; ++u) vt[d8 + u][s] = vv[u];
    }
    __syncthreads();

    ffrag sc[4];
#pragma unroll
    for (int nt = 0; nt < 4; ++nt) sc[nt] = (ffrag){0.f, 0.f, 0.f, 0.f};
#pragma unroll
    for (int kt = 0; kt < 2; ++kt) {
        bfrag a = *(const bfrag*)&qs[wave * 16 + lm][kt * 32 + lq * 8];
#pragma unroll
        for (int nt = 0; nt < 4; ++nt) {
            bfrag b = *(const bfrag*)&ks[nt * 16 + lm][kt * 32 + lq * 8];
            sc[nt] = MFMA16(a, b, sc[nt]);
        }
    }
    __syncthreads();

#pragma unroll
    for (int r = 0; r < 4; ++r) {
        float x[4];
        float mx = -1e30f;
#pragma unroll
        for (int nt = 0; nt < 4; ++nt) {
            int col = nt * 16 + lm;
            x[nt] = (col < len) ? sc[nt][r] * 0.125f : -1e9f;
            mx = fmaxf(mx, x[nt]);
        }
        for (int off = 8; off; off >>= 1) mx = fmaxf(mx, __shfl_xor(mx, off));
        float e[4], se = 0.f;
#pragma unroll
        for (int nt = 0; nt < 4; ++nt) { e[nt] = __expf(x[nt] - mx); se += e[nt]; }
        for (int off = 8; off; off >>= 1) se += __shfl_xor(se, off);
        float inv = 1.f / se;
        int row = wave * 16 + lq * 4 + r;
#pragma unroll
        for (int nt = 0; nt < 4; ++nt)
            qs[row][nt * 16 + lm] = f2b(e[nt] * inv);
    }
    __syncthreads();

    ffrag oc[4];
#pragma unroll
    for (int dt = 0; dt < 4; ++dt) oc[dt] = (ffrag){0.f, 0.f, 0.f, 0.f};
#pragma unroll
    for (int kt = 0; kt < 2; ++kt) {
        bfrag a = *(const bfrag*)&qs[wave * 16 + lm][kt * 32 + lq * 8];
#pragma unroll
        for (int dt = 0; dt < 4; ++dt) {
            bfrag b = *(const bfrag*)&vt[dt * 16 + lm][kt * 32 + lq * 8];
            oc[dt] = MFMA16(a, b, oc[dt]);
        }
    }
#pragma unroll
    for (int r = 0; r < 4; ++r) {
        int i = wave * 16 + lq * 4 + r;
        if (i < SEGL) {
            ushort_t* op = O + (long long)(n * SEGL + i) * DMODEL + h * DHEAD + lm;
#pragma unroll
            for (int dt = 0; dt < 4; ++dt)
                op[dt * 16] = f2b(oc[dt][r]);
        }
    }
}

// ---------------------------------------------------------------------------
// Phase-2 fused KV-projection + cross-attention. One (seq n, head h) block.
// ---------------------------------------------------------------------------
__global__ __launch_bounds__(256) void cross_attn_k(
    const ushort_t* __restrict__ Qp, long long qns, long long qrs,
    const ushort_t* __restrict__ Prev, int pgrp, long long pstride,
    const ushort_t* __restrict__ Wkv,   // [1024][512] bf16 (cWk^T | cWv^T)
    ushort_t* __restrict__ O)
{
    __shared__ ushort_t xp[64 * 264];   // phase A: prev half; phase B: ks|vt
    __shared__ ushort_t qs[64][72];     // Q, then P
    const int n = blockIdx.x >> 3, h = blockIdx.x & 7;
    const int tid = threadIdx.x;
    const int wave = tid >> 6, lane = tid & 63;
    const int lm = lane & 15, lq = lane >> 4;

    // load Q rows
    for (int idx = tid; idx < SEGL * 8; idx += 256) {
        int s = idx >> 3, d8 = (idx & 7) << 3;
        *(uint4*)&qs[s][d8] =
            *(const uint4*)(Qp + (long long)n * qns + (long long)s * qrs + h * DHEAD + d8);
    }

    // KV projection: wave 0/1 -> K cols 0-31/32-63; wave 2/3 -> V cols.
    const ushort_t* wbase = Wkv +
        (long long)((wave >> 1) * 512 + h * 64 + (wave & 1) * 32) * 512;
    ffrag kv[4][2];
#pragma unroll
    for (int i = 0; i < 4; ++i)
#pragma unroll
        for (int j = 0; j < 2; ++j) kv[i][j] = (ffrag){0.f, 0.f, 0.f, 0.f};

#pragma unroll
    for (int half = 0; half < 2; ++half) {
        __syncthreads();   // prior reads of xp done
        for (int idx = tid; idx < 64 * 33; idx += 256) {
            int s = idx / 33, c8 = (idx % 33) * 8;
            uint4 v = {0, 0, 0, 0};
            if (s < SEGL && c8 < 256) {
                long long r = (long long)n * SEGL + s;
                v = *(const uint4*)(Prev + (r / pgrp) * pstride
                                    + (r % pgrp) * DMODEL + half * 256 + c8);
            }
            *(uint4*)&xp[s * 264 + c8] = v;
        }
        __syncthreads();
#pragma unroll
        for (int k8 = 0; k8 < 8; ++k8) {
            const int kg = half * 256 + k8 * 32;
            bfrag bf[2], af[4];
#pragma unroll
            for (int j = 0; j < 2; ++j)
                bf[j] = *(const bfrag*)(wbase + (long long)(j * 16 + lm) * 512 + kg + lq * 8);
#pragma unroll
            for (int i = 0; i < 4; ++i)
                af[i] = *(const bfrag*)&xp[(i * 16 + lm) * 264 + k8 * 32 + lq * 8];
#pragma unroll
            for (int i = 0; i < 4; ++i)
#pragma unroll
                for (int j = 0; j < 2; ++j)
                    kv[i][j] = MFMA16(af[i], bf[j], kv[i][j]);
        }
    }
    __syncthreads();   // all xp reads done before ks/vt overwrite
    ushort_t (*ks)[72] = (ushort_t(*)[72])&xp[0];
    ushort_t (*vt)[72] = (ushort_t(*)[72])&xp[64 * 72];
#pragma unroll
    for (int i = 0; i < 4; ++i)
#pragma unroll
        for (int j = 0; j < 2; ++j)
#pragma unroll
            for (int r = 0; r < 4; ++r) {
                int rowk = i * 16 + lq * 4 + r;
                int d = (wave & 1) * 32 + j * 16 + lm;
                ushort_t val = f2b(kv[i][j][r]);
                if (wave < 2) ks[rowk][d] = val;   // K[rowk][d]
                else          vt[d][rowk] = val;   // V^T[d][rowk]
            }
    __syncthreads();

    // QK^T
    ffrag sc[4];
#pragma unroll
    for (int nt = 0; nt < 4; ++nt) sc[nt] = (ffrag){0.f, 0.f, 0.f, 0.f};
#pragma unroll
    for (int kt = 0; kt < 2; ++kt) {
        bfrag a = *(const bfrag*)&qs[wave * 16 + lm][kt * 32 + lq * 8];
#pragma unroll
        for (int nt = 0; nt < 4; ++nt) {
            bfrag b = *(const bfrag*)&ks[nt * 16 + lm][kt * 32 + lq * 8];
            sc[nt] = MFMA16(a, b, sc[nt]);
        }
    }
    __syncthreads();

#pragma unroll
    for (int r = 0; r < 4; ++r) {
        float x[4];
        float mx = -1e30f;
#pragma unroll
        for (int nt = 0; nt < 4; ++nt) {
            int col = nt * 16 + lm;
            x[nt] = (col < SEGL) ? sc[nt][r] * 0.125f : -1e9f;
            mx = fmaxf(mx, x[nt]);
        }
        for (int off = 8; off; off >>= 1) mx = fmaxf(mx, __shfl_xor(mx, off));
        float e[4], se = 0.f;
#pragma unroll
        for (int nt = 0; nt < 4; ++nt) { e[nt] = __expf(x[nt] - mx); se += e[nt]; }
        for (int off = 8; off; off >>= 1) se += __shfl_xor(se, off);
        float inv = 1.f / se;
        int row = wave * 16 + lq * 4 + r;
#pragma unroll
        for (int nt = 0; nt < 4; ++nt)
            qs[row][nt * 16 + lm] = f2b(e[nt] * inv);
    }
    __syncthreads();

    // PV
    ffrag oc[4];
#pragma unroll
    for (int dt = 0; dt < 4; ++dt) oc[dt] = (ffrag){0.f, 0.f, 0.f, 0.f};
#pragma unroll
    for (int kt = 0; kt < 2; ++kt) {
        bfrag a = *(const bfrag*)&qs[wave * 16 + lm][kt * 32 + lq * 8];
#pragma unroll
        for (int dt = 0; dt < 4; ++dt) {
            bfrag b = *(const bfrag*)&vt[dt * 16 + lm][kt * 32 + lq * 8];
            oc[dt] = MFMA16(a, b, oc[dt]);
        }
    }
#pragma unroll
    for (int r = 0; r < 4; ++r) {
        int i = wave * 16 + lq * 4 + r;
        if (i < SEGL) {
            ushort_t* op = O + (long long)(n * SEGL + i) * DMODEL + h * DHEAD + lm;
#pragma unroll
            for (int dt = 0; dt < 4; ++dt)
                op[dt * 16] = f2b(oc[dt][r]);
        }
    }
}

// ---------------------------------------------------------------------------
// out = LN(a + b)*gamma + beta, rows of 512, bf16 in, bf16/fp32 out. (phase 1)
// ---------------------------------------------------------------------------
template<bool OUTF32>
__global__ __launch_bounds__(256) void add_ln_k(
    const ushort_t* __restrict__ A, int agrp, long long astride,
    const ushort_t* __restrict__ Bv,
    const float* __restrict__ gamma, const float* __restrict__ beta,
    void* __restrict__ O, int ogrp, long long ostride, int M)
{
    const int wave = threadIdx.x >> 6, lane = threadIdx.x & 63;
    const int r = blockIdx.x * 4 + wave;
    if (r >= M) return;
    const ushort_t* a = A + (long long)(r / agrp) * astride + (long long)(r % agrp) * DMODEL;
    const ushort_t* b = Bv + (long long)r * DMODEL;
    float x[8];
    {
        uint4 a4 = *(const uint4*)(a + lane * 8);
        uint4 b4 = *(const uint4*)(b + lane * 8);
        const unsigned* aa = (const unsigned*)&a4;
        const unsigned* bb = (const unsigned*)&b4;
#pragma unroll
        for (int c = 0; c < 4; ++c) {
            union { unsigned u; float f; } alo, ahi, blo, bhi;
            alo.u = aa[c] << 16; ahi.u = aa[c] & 0xffff0000u;
            blo.u = bb[c] << 16; bhi.u = bb[c] & 0xffff0000u;
            x[2 * c]     = alo.f + blo.f;
            x[2 * c + 1] = ahi.f + bhi.f;
        }
    }
    float s = 0.f, s2 = 0.f;
#pragma unroll
    for (int i = 0; i < 8; ++i) { s += x[i]; s2 = fmaf(x[i], x[i], s2); }
    for (int off = 32; off; off >>= 1) {
        s += __shfl_xor(s, off);
        s2 += __shfl_xor(s2, off);
    }
    const float mean = s * (1.f / DMODEL);
    const float var = s2 * (1.f / DMODEL) - mean * mean;
    const float inv = rsqrtf(var + 1e-5f);
    float4 g0 = *(const float4*)(gamma + lane * 8);
    float4 g1 = *(const float4*)(gamma + lane * 8 + 4);
    float4 be0 = *(const float4*)(beta + lane * 8);
    float4 be1 = *(const float4*)(beta + lane * 8 + 4);
    float y[8];
    y[0] = (x[0] - mean) * inv * g0.x + be0.x;
    y[1] = (x[1] - mean) * inv * g0.y + be0.y;
    y[2] = (x[2] - mean) * inv * g0.z + be0.z;
    y[3] = (x[3] - mean) * inv * g0.w + be0.w;
    y[4] = (x[4] - mean) * inv * g1.x + be1.x;
    y[5] = (x[5] - mean) * inv * g1.y + be1.y;
    y[6] = (x[6] - mean) * inv * g1.z + be1.z;
    y[7] = (x[7] - mean) * inv * g1.w + be1.w;
    if (OUTF32) {
        float* o = (float*)O + (long long)(r / ogrp) * ostride + (long long)(r % ogrp) * DMODEL;
        *(float4*)(o + lane * 8) = *(float4*)&y[0];
        *(float4*)(o + lane * 8 + 4) = *(float4*)&y[4];
    } else {
        ushort_t* o = (ushort_t*)O + (long long)(r / ogrp) * ostride + (long long)(r % ogrp) * DMODEL;
        ushort_t ob[8];
#pragma unroll
        for (int i = 0; i < 8; ++i) ob[i] = f2b(y[i]);
        *(uint4*)(o + lane * 8) = *(const uint4*)ob;
    }
}

__global__ void lens_k(const int* __restrict__ ends, int* __restrict__ lens)
{
    int i = blockIdx.x * 256 + threadIdx.x;
    if (i >= NB * NT) return;
    int t = i & (NT - 1);
    int prev = t ? ends[i - 1] : 0;
    int l = ends[i] - prev;
    if (l > SEGL) l = SEGL;
    lens[i] = l;
}

// ---------------------------------------------------------------------------
extern "C" void kernel_launch(void* const* d_in, const int* in_sizes, int n_in,
                              void* d_out, int out_size, void* d_ws, size_t ws_size,
                              hipStream_t stream)
{
    const float* seqs = (const float*)d_in[0];
    const int*   ends = (const int*)d_in[1];
    const float* eG1 = (const float*)d_in[7],  *eB1 = (const float*)d_in[8];
    const float* eG2 = (const float*)d_in[11], *eB2 = (const float*)d_in[12];
    const float* cG1 = (const float*)d_in[17], *cB1 = (const float*)d_in[18];
    const float* cG2 = (const float*)d_in[21], *cB2 = (const float*)d_in[22];
    float* out = (float*)d_out;

    const int G = (ws_size >= (size_t)470000000) ? 8 : 4;
    const long long CH = 1638400LL * G;

    ushort_t* ws = (ushort_t*)d_ws;
    const long long SEQROW = (long long)NT * SEGL * DMODEL;    // 409600
    ushort_t* SEQB = ws;
    ushort_t* WT   = SEQB + 26214400LL;
    ushort_t* ENC  = WT   + 6553600LL;
    ushort_t* BUF0 = ENC  + 26214400LL;
    ushort_t* QKV  = BUF0 + CH;
    ushort_t* BUF4 = QKV  + 3 * CH;
    ushort_t* BUF1 = BUF4 + CH;
    ushort_t* BUF2 = BUF1 + CH;
    ushort_t* MID  = BUF2 + CH;
    ushort_t* OUTB = MID  + 4 * CH;
    ushort_t* QALL = OUTB + 1638400LL;
    int*      lens = (int*)(QALL + 24576000LL);

    const ushort_t* eWinT = WT + 0;
    const ushort_t* WQKVe = WT + 262144;      // 1536 x 512
    const ushort_t* eWoT  = WT + 1048576;
    const ushort_t* eF1T  = WT + 1310720;     // 2048 x 512
    const ushort_t* eF2T  = WT + 2359296;     // 512 x 2048
    const ushort_t* cWqT  = WT + 3407872;
    const ushort_t* cKV   = WT + 3670016;     // 1024 x 512 (cWk^T | cWv^T)
    const ushort_t* cWoT  = WT + 4194304;
    const ushort_t* cF1T  = WT + 4456448;
    const ushort_t* cF2T  = WT + 5505024;

    struct WMap { int src; long long dst; int K, N; };
    const WMap wm[13] = {
        {2,  0,       512, 512},
        {3,  262144,  512, 512},
        {4,  524288,  512, 512},
        {5,  786432,  512, 512},
        {6,  1048576, 512, 512},
        {9,  1310720, 512, 2048},
        {10, 2359296, 2048, 512},
        {13, 3407872, 512, 512},
        {14, 3670016, 512, 512},
        {15, 3932160, 512, 512},
        {16, 4194304, 512, 512},
        {19, 4456448, 512, 2048},
        {20, 5505024, 2048, 512},
    };

    cvt_k<<<12800, 256, 0, stream>>>(seqs, SEQB, 26214400LL);
    for (int w = 0; w < 13; ++w) {
        dim3 g(wm[w].N / 32, wm[w].K / 32);
        wtrans_k<<<g, 256, 0, stream>>>((const float*)d_in[wm[w].src],
                                        WT + wm[w].dst, wm[w].K, wm[w].N);
    }
    lens_k<<<4, 256, 0, stream>>>(ends, lens);

    auto gemmL = [&](const ushort_t* A, int agrp, long long astr, const ushort_t* Bt,
                     ushort_t* C, int M, int N, int K, int relu) {
        dim3 g(N / 128, M / 128);
        mfma_gemm<128, 128, 2, 2><<<g, 256, 0, stream>>>(A, agrp, astr, Bt, C, M, N, K, relu);
    };
    // phase-2 F1 GEMM: 64x64 tiles (proven round-8 config)
    auto gemmS = [&](const ushort_t* A, int agrp, long long astr, const ushort_t* Bt,
                     ushort_t* C, int M, int N, int K, int relu) {
        dim3 g(N / 64, M / 64);
        mfma_gemm<64, 64, 2, 2><<<g, 256, 0, stream>>>(A, agrp, astr, Bt, C, M, N, K, relu);
    };

    // gemm_ln_k dynamic LDS (147456 B > 64KB static limit)
    constexpr int GLN_LDS = 2 * 36864 * 2;   // 147456 bytes
    static bool attr_set = false;
    if (!attr_set) {
        hipFuncSetAttribute((const void*)gemm_ln_k<false>,
                            hipFuncAttributeMaxDynamicSharedMemorySize, GLN_LDS);
        hipFuncSetAttribute((const void*)gemm_ln_k<true>,
                            hipFuncAttributeMaxDynamicSharedMemorySize, GLN_LDS);
        attr_set = true;
    }

    // ---------------- Phase 1: all encoders, chunks of G segments ----------
    const int Mc = NB * G * SEGL;
    for (int c = 0; c < NT / G; ++c) {
        const int t0 = c * G;
        const ushort_t* Abase = SEQB + (long long)t0 * SEGL * DMODEL;
        ushort_t* ENCc = ENC + (long long)t0 * SEGL * DMODEL;
        gemmL(Abase, G * SEGL, SEQROW, eWinT, BUF0, Mc, 512, 512, 0);
        gemmL(BUF0, Mc, 0, WQKVe, QKV, Mc, 1536, 512, 0);
        attn_mfma_k<<<NB * G * NHEAD, 256, 0, stream>>>(
            QKV, 50LL * 1536, 1536, QKV + 512, QKV + 1024, 50LL * 1536, 1536,
            BUF4, lens, G, t0);
        gemmL(BUF4, Mc, 0, eWoT, BUF1, Mc, 512, 512, 0);
        add_ln_k<false><<<Mc / 4, 256, 0, stream>>>(BUF0, Mc, 0, BUF1, eG1, eB1,
                                                    BUF2, Mc, 0, Mc);
        gemmL(BUF2, Mc, 0, eF1T, MID, Mc, 2048, 512, 1);
        gemmL(MID, Mc, 0, eF2T, BUF1, Mc, 512, 2048, 0);
        add_ln_k<false><<<Mc / 4, 256, 0, stream>>>(BUF2, Mc, 0, BUF1, eG2, eB2,
                                                    ENCc, G * SEGL, SEQROW, Mc);
    }

    // Batched Q projections for ALL phase-2 steps
    gemmL(ENC + 25600, 750, SEQROW, cWqT, QALL, 48000, 512, 512, 0);

    // ---------------- Phase 2: 15 sequential steps, 4 launches each --------
    const int Ms = NB * SEGL;   // 3200
    for (int t = 1; t < NT; ++t) {
        const ushort_t* currA = ENC + (long long)t * SEGL * DMODEL;
        const ushort_t* prevA; int pg; long long ps;
        if (t == 1) { prevA = ENC;  pg = SEGL; ps = SEQROW; }
        else        { prevA = OUTB; pg = Ms;   ps = 0; }
        // 1) fused KV-projection + cross-attention -> BUF4
        cross_attn_k<<<NB * NHEAD, 256, 0, stream>>>(
            QALL + (long long)(t - 1) * 25600, 750LL * 512, 512,
            prevA, pg, ps, cKV, BUF4);
        // 2) fused Wo GEMM + add(curr) + LN1 -> BUF2
        gemm_ln_k<false><<<Ms / 64, 512, GLN_LDS, stream>>>(
            BUF4, Ms, 0, cWoT, 512, currA, SEGL, SEQROW, cG1, cB1, BUF2);
        // 3) F1 GEMM + relu -> MID
        gemmS(BUF2, Ms, 0, cF1T, MID, Ms, 2048, 512, 1);
        // 4) fused F2 GEMM + add(BUF2) + LN2 -> OUTB (f32 out on last step)
        if (t == NT - 1)
            gemm_ln_k<true><<<Ms / 64, 512, GLN_LDS, stream>>>(
                MID, Ms, 0, cF2T, 2048, BUF2, Ms, 0, cG2, cB2, out);
        else
            gemm_ln_k<false><<<Ms / 64, 512, GLN_LDS, stream>>>(
                MID, Ms, 0, cF2T, 2048, BUF2, Ms, 0, cG2, cB2, OUTB);
    }
}

// Round 7
// 3227.224 us; speedup vs baseline: 3.3547x; 1.1633x over previous
//
#include <hip/hip_runtime.h>

// RecurrentTransformerEncoder on MI355X — round 15: revert to the verified
// round-8 6-launch phase-2 structure (round-14 GEMM+LN fusion forced 50-block
// grids -> 94us GEMMs), and raise phase-2 GEMM parallelism instead: the
// proven mfma_gemm template instantiated at 32x64 tiles (LDS 24KB -> 6
// blocks/CU) gives Wo/F2 800 blocks and F1 3200 blocks (was 400/1600).
// Rule from rounds 12-14: <400-block phase-2 configs are latency-crushed.
// B=64, T=16, SEG=50, E=D=512, H=8, DH=64, F=2048.

#define NB   64
#define NT   16
#define SEGL 50
#define DMODEL 512
#define DFF  2048
#define NHEAD 8
#define DHEAD 64

typedef unsigned short ushort_t;
typedef __attribute__((ext_vector_type(8))) short bfrag;   // 8 bf16 (4 VGPRs)
typedef __attribute__((ext_vector_type(4))) float ffrag;   // 4 fp32 acc

__device__ __forceinline__ ushort_t f2b(float x) {
    union { float f; unsigned u; } c; c.f = x;
    unsigned r = c.u + 0x7fffu + ((c.u >> 16) & 1u);
    return (ushort_t)(r >> 16);
}

#define GLOAD_LDS16(g, l) __builtin_amdgcn_global_load_lds( \
    (const __attribute__((address_space(1))) void*)(g),      \
    (__attribute__((address_space(3))) void*)(l), 16, 0, 0)

#define MFMA16(a, b, c) __builtin_amdgcn_mfma_f32_16x16x32_bf16(a, b, c, 0, 0, 0)

// ---------------------------------------------------------------------------
// MFMA GEMM (LDS-staged, BK=64 dbuf): C = relu?(A @ Bt^T), bf16.
// A rows remapped: row m at A + (m/agrp)*astride + (m%agrp)*K.
// Instantiations: <128,128,2,2> (phase-1), <32,64,1,4> (phase-2, 24KB LDS).
// ---------------------------------------------------------------------------
template<int BM, int BN, int WROWS, int WCOLS>
__global__ __launch_bounds__(256) void mfma_gemm(
    const ushort_t* __restrict__ A, int agrp, long long astride,
    const ushort_t* __restrict__ Bt, ushort_t* __restrict__ C,
    int M, int N, int K, int relu)
{
    constexpr int WM = BM / WROWS, WN = BN / WCOLS;
    constexpr int SM = WM / 16, SN = WN / 16;
    constexpr int NSUBA = BM / 16, NSUBB = BN / 16;
    constexpr int NSUB = NSUBA + NSUBB;
    constexpr int NINST = NSUB * 2;
    constexpr int IPW = NINST / 4;
    constexpr int BUFS = NSUB * 1024;
    constexpr int EST = WN + 8;
    constexpr int LDS_KLOOP = 2 * BUFS;
    constexpr int LDS_EPI   = 4 * WM * EST;
    constexpr int LDS_SZ = LDS_KLOOP > LDS_EPI ? LDS_KLOOP : LDS_EPI;
    __shared__ ushort_t lds[LDS_SZ];

    const int tid = threadIdx.x;
    const int wave = tid >> 6, lane = tid & 63;
    const int wrow = wave / WCOLS, wcol = wave % WCOLS;
    const int bm = blockIdx.y * BM, bn = blockIdx.x * BN;
    const int lm = lane & 15, lq = lane >> 4;

    ffrag acc[SM][SN];
#pragma unroll
    for (int i = 0; i < SM; ++i)
#pragma unroll
        for (int j = 0; j < SN; ++j) acc[i][j] = (ffrag){0.f, 0.f, 0.f, 0.f};

    const ushort_t* gptr[IPW];
    int loff[IPW];
#pragma unroll
    for (int e = 0; e < IPW; ++e) {
        int g = wave * IPW + e;
        int s = g >> 1, h = g & 1;
        if (s < NSUBA) {
            int m = bm + s * 16 + lm;
            gptr[e] = A + (long long)(m / agrp) * astride
                        + (long long)(m % agrp) * K + h * 32 + lq * 8;
        } else {
            int n = bn + (s - NSUBA) * 16 + lm;
            gptr[e] = Bt + (long long)n * K + h * 32 + lq * 8;
        }
        loff[e] = s * 1024 + h * 512;
    }

#pragma unroll
    for (int e = 0; e < IPW; ++e)
        GLOAD_LDS16(gptr[e], &lds[loff[e]]);

    const int nk = K >> 6;
    for (int kk = 0; kk < nk; ++kk) {
        __syncthreads();
        if (kk + 1 < nk) {
            const int koff = (kk + 1) << 6;
            const int nb = (kk + 1) & 1;
#pragma unroll
            for (int e = 0; e < IPW; ++e)
                GLOAD_LDS16(gptr[e] + koff, &lds[nb * BUFS + loff[e]]);
        }
        const ushort_t* lb = &lds[(kk & 1) * BUFS];
#pragma unroll
        for (int h = 0; h < 2; ++h) {
            bfrag af[SM], bfg[SN];
#pragma unroll
            for (int i = 0; i < SM; ++i)
                af[i] = *(const bfrag*)&lb[(wrow * SM + i) * 1024 + h * 512 + lane * 8];
#pragma unroll
            for (int j = 0; j < SN; ++j)
                bfg[j] = *(const bfrag*)&lb[(NSUBA + wcol * SN + j) * 1024 + h * 512 + lane * 8];
#pragma unroll
            for (int i = 0; i < SM; ++i)
#pragma unroll
                for (int j = 0; j < SN; ++j)
                    acc[i][j] = MFMA16(af[i], bfg[j], acc[i][j]);
        }
    }

    __syncthreads();
    ushort_t* ep = &lds[wave * WM * EST];
#pragma unroll
    for (int i = 0; i < SM; ++i)
#pragma unroll
        for (int j = 0; j < SN; ++j)
#pragma unroll
            for (int r = 0; r < 4; ++r) {
                int row = i * 16 + lq * 4 + r;
                int col = j * 16 + lm;
                float v = acc[i][j][r];
                if (relu) v = fmaxf(v, 0.f);
                ep[row * EST + col] = f2b(v);
            }
    constexpr int CPR = WN / 8;
    constexpr int RPI = 64 / CPR;
    const int lrow = lane / CPR, lcol = (lane % CPR) * 8;
#pragma unroll
    for (int it = 0; it < WM / RPI; ++it) {
        int row = it * RPI + lrow;
        uint4 v = *(const uint4*)&ep[row * EST + lcol];
        long long grow = bm + wrow * WM + row;
        int gcol = bn + wcol * WN + lcol;
        *(uint4*)&C[grow * N + gcol] = v;
    }
}

// ---------------------------------------------------------------------------
__global__ __launch_bounds__(256) void wtrans_k(
    const float* __restrict__ W, ushort_t* __restrict__ Wt, int K, int N)
{
    __shared__ float t[32][33];
    const int bk = blockIdx.y * 32, bn = blockIdx.x * 32;
    const int tx = threadIdx.x & 31, ty = threadIdx.x >> 5;
    for (int i = ty; i < 32; i += 8)
        t[i][tx] = W[(long long)(bk + i) * N + bn + tx];
    __syncthreads();
    for (int i = ty; i < 32; i += 8)
        Wt[(long long)(bn + i) * K + bk + tx] = f2b(t[tx][i]);
}

__global__ __launch_bounds__(256) void cvt_k(
    const float* __restrict__ in, ushort_t* __restrict__ out, long long n)
{
    long long i = ((long long)blockIdx.x * 256 + threadIdx.x) * 8;
    if (i >= n) return;
    float4 a = *(const float4*)(in + i);
    float4 b = *(const float4*)(in + i + 4);
    ushort_t o[8] = {f2b(a.x), f2b(a.y), f2b(a.z), f2b(a.w),
                     f2b(b.x), f2b(b.y), f2b(b.z), f2b(b.w)};
    *(uint4*)(out + i) = *(const uint4*)o;
}

// ---------------------------------------------------------------------------
// Phase-1 MFMA attention, one (sequence n, head h) per block. S=50->64, D=64.
// ---------------------------------------------------------------------------
__global__ __launch_bounds__(256) void attn_mfma_k(
    const ushort_t* __restrict__ Q, long long qns, long long qrs,
    const ushort_t* __restrict__ K, const ushort_t* __restrict__ V,
    long long kns, long long kvrs,
    ushort_t* __restrict__ O,
    const int* __restrict__ lens, int G, int t0)
{
    __shared__ ushort_t qs[64][72];   // Q, then P
    __shared__ ushort_t ks[64][72];
    __shared__ ushort_t vt[64][72];   // V^T
    const int n = blockIdx.x >> 3, h = blockIdx.x & 7;
    const int tid = threadIdx.x;
    const int wave = tid >> 6, lane = tid & 63;
    const int lm = lane & 15, lq = lane >> 4;
    int len = SEGL;
    if (lens) {
        int b = n / G, t = t0 + (n % G);
        len = lens[b * NT + t];
        if (len > SEGL) len = SEGL;
    }
    {
        uint4 z = {0, 0, 0, 0};
        uint4* vz = (uint4*)&vt[0][0];
        for (int i = tid; i < 64 * 72 / 8; i += 256) vz[i] = z;
    }
    __syncthreads();
    for (int idx = tid; idx < SEGL * 8; idx += 256) {
        int s = idx >> 3, d8 = (idx & 7) << 3;
        const ushort_t* qp = Q + (long long)n * qns + (long long)s * qrs + h * DHEAD + d8;
        const ushort_t* kp = K + (long long)n * kns + (long long)s * kvrs + h * DHEAD + d8;
        const ushort_t* vp = V + (long long)n * kns + (long long)s * kvrs + h * DHEAD + d8;
        *(uint4*)&qs[s][d8] = *(const uint4*)qp;
        *(uint4*)&ks[s][d8] = *(const uint4*)kp;
        uint4 v4 = *(const uint4*)vp;
        const ushort_t* vv = (const ushort_t*)&v4;
#pragma unroll
        for (int u = 0; u < 8; ++u) vt[d8 + u][s] = vv[u];
    }
    __syncthreads();

    ffrag sc[4];
#pragma unroll
    for (int nt = 0; nt < 4; ++nt) sc[nt] = (ffrag){0.f, 0.f, 0.f, 0.f};
#pragma unroll
    for (int kt = 0; kt < 2; ++kt) {
        bfrag a = *(const bfrag*)&qs[wave * 16 + lm][kt * 32 + lq * 8];
#pragma unroll
        for (int nt = 0; nt < 4; ++nt) {
            bfrag b = *(const bfrag*)&ks[nt * 16 + lm][kt * 32 + lq * 8];
            sc[nt] = MFMA16(a, b, sc[nt]);
        }
    }
    __syncthreads();

#pragma unroll
    for (int r = 0; r < 4; ++r) {
        float x[4];
        float mx = -1e30f;
#pragma unroll
        for (int nt = 0; nt < 4; ++nt) {
            int col = nt * 16 + lm;
            x[nt] = (col < len) ? sc[nt][r] * 0.125f : -1e9f;
            mx = fmaxf(mx, x[nt]);
        }
        for (int off = 8; off; off >>= 1) mx = fmaxf(mx, __shfl_xor(mx, off));
        float e[4], se = 0.f;
#pragma unroll
        for (int nt = 0; nt < 4; ++nt) { e[nt] = __expf(x[nt] - mx); se += e[nt]; }
        for (int off = 8; off; off >>= 1) se += __shfl_xor(se, off);
        float inv = 1.f / se;
        int row = wave * 16 + lq * 4 + r;
#pragma unroll
        for (int nt = 0; nt < 4; ++nt)
            qs[row][nt * 16 + lm] = f2b(e[nt] * inv);
    }
    __syncthreads();

    ffrag oc[4];
#pragma unroll
    for (int dt = 0; dt < 4; ++dt) oc[dt] = (ffrag){0.f, 0.f, 0.f, 0.f};
#pragma unroll
    for (int kt = 0; kt < 2; ++kt) {
        bfrag a = *(const bfrag*)&qs[wave * 16 + lm][kt * 32 + lq * 8];
#pragma unroll
        for (int dt = 0; dt < 4; ++dt) {
            bfrag b = *(const bfrag*)&vt[dt * 16 + lm][kt * 32 + lq * 8];
            oc[dt] = MFMA16(a, b, oc[dt]);
        }
    }
#pragma unroll
    for (int r = 0; r < 4; ++r) {
        int i = wave * 16 + lq * 4 + r;
        if (i < SEGL) {
            ushort_t* op = O + (long long)(n * SEGL + i) * DMODEL + h * DHEAD + lm;
#pragma unroll
            for (int dt = 0; dt < 4; ++dt)
                op[dt * 16] = f2b(oc[dt][r]);
        }
    }
}

// ---------------------------------------------------------------------------
// Phase-2 fused KV-projection + cross-attention. One (seq n, head h) block.
// ---------------------------------------------------------------------------
__global__ __launch_bounds__(256) void cross_attn_k(
    const ushort_t* __restrict__ Qp, long long qns, long long qrs,
    const ushort_t* __restrict__ Prev, int pgrp, long long pstride,
    const ushort_t* __restrict__ Wkv,   // [1024][512] bf16 (cWk^T | cWv^T)
    ushort_t* __restrict__ O)
{
    __shared__ ushort_t xp[64 * 264];   // phase A: prev half; phase B: ks|vt
    __shared__ ushort_t qs[64][72];     // Q, then P
    const int n = blockIdx.x >> 3, h = blockIdx.x & 7;
    const int tid = threadIdx.x;
    const int wave = tid >> 6, lane = tid & 63;
    const int lm = lane & 15, lq = lane >> 4;

    // load Q rows
    for (int idx = tid; idx < SEGL * 8; idx += 256) {
        int s = idx >> 3, d8 = (idx & 7) << 3;
        *(uint4*)&qs[s][d8] =
            *(const uint4*)(Qp + (long long)n * qns + (long long)s * qrs + h * DHEAD + d8);
    }

    // KV projection: wave 0/1 -> K cols 0-31/32-63; wave 2/3 -> V cols.
    const ushort_t* wbase = Wkv +
        (long long)((wave >> 1) * 512 + h * 64 + (wave & 1) * 32) * 512;
    ffrag kv[4][2];
#pragma unroll
    for (int i = 0; i < 4; ++i)
#pragma unroll
        for (int j = 0; j < 2; ++j) kv[i][j] = (ffrag){0.f, 0.f, 0.f, 0.f};

#pragma unroll
    for (int half = 0; half < 2; ++half) {
        __syncthreads();   // prior reads of xp done
        for (int idx = tid; idx < 64 * 33; idx += 256) {
            int s = idx / 33, c8 = (idx % 33) * 8;
            uint4 v = {0, 0, 0, 0};
            if (s < SEGL && c8 < 256) {
                long long r = (long long)n * SEGL + s;
                v = *(const uint4*)(Prev + (r / pgrp) * pstride
                                    + (r % pgrp) * DMODEL + half * 256 + c8);
            }
            *(uint4*)&xp[s * 264 + c8] = v;
        }
        __syncthreads();
#pragma unroll
        for (int k8 = 0; k8 < 8; ++k8) {
            const int kg = half * 256 + k8 * 32;
            bfrag bf[2], af[4];
#pragma unroll
            for (int j = 0; j < 2; ++j)
                bf[j] = *(const bfrag*)(wbase + (long long)(j * 16 + lm) * 512 + kg + lq * 8);
#pragma unroll
            for (int i = 0; i < 4; ++i)
                af[i] = *(const bfrag*)&xp[(i * 16 + lm) * 264 + k8 * 32 + lq * 8];
#pragma unroll
            for (int i = 0; i < 4; ++i)
#pragma unroll
                for (int j = 0; j < 2; ++j)
                    kv[i][j] = MFMA16(af[i], bf[j], kv[i][j]);
        }
    }
    __syncthreads();   // all xp reads done before ks/vt overwrite
    ushort_t (*ks)[72] = (ushort_t(*)[72])&xp[0];
    ushort_t (*vt)[72] = (ushort_t(*)[72])&xp[64 * 72];
#pragma unroll
    for (int i = 0; i < 4; ++i)
#pragma unroll
        for (int j = 0; j < 2; ++j)
#pragma unroll
            for (int r = 0; r < 4; ++r) {
                int rowk = i * 16 + lq * 4 + r;
                int d = (wave & 1) * 32 + j * 16 + lm;
                ushort_t val = f2b(kv[i][j][r]);
                if (wave < 2) ks[rowk][d] = val;   // K[rowk][d]
                else          vt[d][rowk] = val;   // V^T[d][rowk]
            }
    __syncthreads();

    // QK^T
    ffrag sc[4];
#pragma unroll
    for (int nt = 0; nt < 4; ++nt) sc[nt] = (ffrag){0.f, 0.f, 0.f, 0.f};
#pragma unroll
    for (int kt = 0; kt < 2; ++kt) {
        bfrag a = *(const bfrag*)&qs[wave * 16 + lm][kt * 32 + lq * 8];
#pragma unroll
        for (int nt = 0; nt < 4; ++nt) {
            bfrag b = *(const bfrag*)&ks[nt * 16 + lm][kt * 32 + lq * 8];
            sc[nt] = MFMA16(a, b, sc[nt]);
        }
    }
    __syncthreads();

#pragma unroll
    for (int r = 0; r < 4; ++r) {
        float x[4];
        float mx = -1e30f;
#pragma unroll
        for (int nt = 0; nt < 4; ++nt) {
            int col = nt * 16 + lm;
            x[nt] = (col < SEGL) ? sc[nt][r] * 0.125f : -1e9f;
            mx = fmaxf(mx, x[nt]);
        }
        for (int off = 8; off; off >>= 1) mx = fmaxf(mx, __shfl_xor(mx, off));
        float e[4], se = 0.f;
#pragma unroll
        for (int nt = 0; nt < 4; ++nt) { e[nt] = __expf(x[nt] - mx); se += e[nt]; }
        for (int off = 8; off; off >>= 1) se += __shfl_xor(se, off);
        float inv = 1.f / se;
        int row = wave * 16 + lq * 4 + r;
#pragma unroll
        for (int nt = 0; nt < 4; ++nt)
            qs[row][nt * 16 + lm] = f2b(e[nt] * inv);
    }
    __syncthreads();

    // PV
    ffrag oc[4];
#pragma unroll
    for (int dt = 0; dt < 4; ++dt) oc[dt] = (ffrag){0.f, 0.f, 0.f, 0.f};
#pragma unroll
    for (int kt = 0; kt < 2; ++kt) {
        bfrag a = *(const bfrag*)&qs[wave * 16 + lm][kt * 32 + lq * 8];
#pragma unroll
        for (int dt = 0; dt < 4; ++dt) {
            bfrag b = *(const bfrag*)&vt[dt * 16 + lm][kt * 32 + lq * 8];
            oc[dt] = MFMA16(a, b, oc[dt]);
        }
    }
#pragma unroll
    for (int r = 0; r < 4; ++r) {
        int i = wave * 16 + lq * 4 + r;
        if (i < SEGL) {
            ushort_t* op = O + (long long)(n * SEGL + i) * DMODEL + h * DHEAD + lm;
#pragma unroll
            for (int dt = 0; dt < 4; ++dt)
                op[dt * 16] = f2b(oc[dt][r]);
        }
    }
}

// ---------------------------------------------------------------------------
// out = LN(a + b)*gamma + beta, rows of 512, bf16 in, bf16/fp32 out.
// ---------------------------------------------------------------------------
template<bool OUTF32>
__global__ __launch_bounds__(256) void add_ln_k(
    const ushort_t* __restrict__ A, int agrp, long long astride,
    const ushort_t* __restrict__ Bv,
    const float* __restrict__ gamma, const float* __restrict__ beta,
    void* __restrict__ O, int ogrp, long long ostride, int M)
{
    const int wave = threadIdx.x >> 6, lane = threadIdx.x & 63;
    const int r = blockIdx.x * 4 + wave;
    if (r >= M) return;
    const ushort_t* a = A + (long long)(r / agrp) * astride + (long long)(r % agrp) * DMODEL;
    const ushort_t* b = Bv + (long long)r * DMODEL;
    float x[8];
    {
        uint4 a4 = *(const uint4*)(a + lane * 8);
        uint4 b4 = *(const uint4*)(b + lane * 8);
        const unsigned* aa = (const unsigned*)&a4;
        const unsigned* bb = (const unsigned*)&b4;
#pragma unroll
        for (int c = 0; c < 4; ++c) {
            union { unsigned u; float f; } alo, ahi, blo, bhi;
            alo.u = aa[c] << 16; ahi.u = aa[c] & 0xffff0000u;
            blo.u = bb[c] << 16; bhi.u = bb[c] & 0xffff0000u;
            x[2 * c]     = alo.f + blo.f;
            x[2 * c + 1] = ahi.f + bhi.f;
        }
    }
    float s = 0.f, s2 = 0.f;
#pragma unroll
    for (int i = 0; i < 8; ++i) { s += x[i]; s2 = fmaf(x[i], x[i], s2); }
    for (int off = 32; off; off >>= 1) {
        s += __shfl_xor(s, off);
        s2 += __shfl_xor(s2, off);
    }
    const float mean = s * (1.f / DMODEL);
    const float var = s2 * (1.f / DMODEL) - mean * mean;
    const float inv = rsqrtf(var + 1e-5f);
    float4 g0 = *(const float4*)(gamma + lane * 8);
    float4 g1 = *(const float4*)(gamma + lane * 8 + 4);
    float4 be0 = *(const float4*)(beta + lane * 8);
    float4 be1 = *(const float4*)(beta + lane * 8 + 4);
    float y[8];
    y[0] = (x[0] - mean) * inv * g0.x + be0.x;
    y[1] = (x[1] - mean) * inv * g0.y + be0.y;
    y[2] = (x[2] - mean) * inv * g0.z + be0.z;
    y[3] = (x[3] - mean) * inv * g0.w + be0.w;
    y[4] = (x[4] - mean) * inv * g1.x + be1.x;
    y[5] = (x[5] - mean) * inv * g1.y + be1.y;
    y[6] = (x[6] - mean) * inv * g1.z + be1.z;
    y[7] = (x[7] - mean) * inv * g1.w + be1.w;
    if (OUTF32) {
        float* o = (float*)O + (long long)(r / ogrp) * ostride + (long long)(r % ogrp) * DMODEL;
        *(float4*)(o + lane * 8) = *(float4*)&y[0];
        *(float4*)(o + lane * 8 + 4) = *(float4*)&y[4];
    } else {
        ushort_t* o = (ushort_t*)O + (long long)(r / ogrp) * ostride + (long long)(r % ogrp) * DMODEL;
        ushort_t ob[8];
#pragma unroll
        for (int i = 0; i < 8; ++i) ob[i] = f2b(y[i]);
        *(uint4*)(o + lane * 8) = *(const uint4*)ob;
    }
}

__global__ void lens_k(const int* __restrict__ ends, int* __restrict__ lens)
{
    int i = blockIdx.x * 256 + threadIdx.x;
    if (i >= NB * NT) return;
    int t = i & (NT - 1);
    int prev = t ? ends[i - 1] : 0;
    int l = ends[i] - prev;
    if (l > SEGL) l = SEGL;
    lens[i] = l;
}

// ---------------------------------------------------------------------------
extern "C" void kernel_launch(void* const* d_in, const int* in_sizes, int n_in,
                              void* d_out, int out_size, void* d_ws, size_t ws_size,
                              hipStream_t stream)
{
    const float* seqs = (const float*)d_in[0];
    const int*   ends = (const int*)d_in[1];
    const float* eG1 = (const float*)d_in[7],  *eB1 = (const float*)d_in[8];
    const float* eG2 = (const float*)d_in[11], *eB2 = (const float*)d_in[12];
    const float* cG1 = (const float*)d_in[17], *cB1 = (const float*)d_in[18];
    const float* cG2 = (const float*)d_in[21], *cB2 = (const float*)d_in[22];
    float* out = (float*)d_out;

    const int G = (ws_size >= (size_t)470000000) ? 8 : 4;
    const long long CH = 1638400LL * G;

    ushort_t* ws = (ushort_t*)d_ws;
    const long long SEQROW = (long long)NT * SEGL * DMODEL;    // 409600
    ushort_t* SEQB = ws;
    ushort_t* WT   = SEQB + 26214400LL;
    ushort_t* ENC  = WT   + 6553600LL;
    ushort_t* BUF0 = ENC  + 26214400LL;
    ushort_t* QKV  = BUF0 + CH;
    ushort_t* BUF4 = QKV  + 3 * CH;
    ushort_t* BUF1 = BUF4 + CH;
    ushort_t* BUF2 = BUF1 + CH;
    ushort_t* MID  = BUF2 + CH;
    ushort_t* OUTB = MID  + 4 * CH;
    ushort_t* QALL = OUTB + 1638400LL;
    int*      lens = (int*)(QALL + 24576000LL);

    const ushort_t* eWinT = WT + 0;
    const ushort_t* WQKVe = WT + 262144;      // 1536 x 512
    const ushort_t* eWoT  = WT + 1048576;
    const ushort_t* eF1T  = WT + 1310720;     // 2048 x 512
    const ushort_t* eF2T  = WT + 2359296;     // 512 x 2048
    const ushort_t* cWqT  = WT + 3407872;
    const ushort_t* cKV   = WT + 3670016;     // 1024 x 512 (cWk^T | cWv^T)
    const ushort_t* cWoT  = WT + 4194304;
    const ushort_t* cF1T  = WT + 4456448;
    const ushort_t* cF2T  = WT + 5505024;

    struct WMap { int src; long long dst; int K, N; };
    const WMap wm[13] = {
        {2,  0,       512, 512},
        {3,  262144,  512, 512},
        {4,  524288,  512, 512},
        {5,  786432,  512, 512},
        {6,  1048576, 512, 512},
        {9,  1310720, 512, 2048},
        {10, 2359296, 2048, 512},
        {13, 3407872, 512, 512},
        {14, 3670016, 512, 512},
        {15, 3932160, 512, 512},
        {16, 4194304, 512, 512},
        {19, 4456448, 512, 2048},
        {20, 5505024, 2048, 512},
    };

    cvt_k<<<12800, 256, 0, stream>>>(seqs, SEQB, 26214400LL);
    for (int w = 0; w < 13; ++w) {
        dim3 g(wm[w].N / 32, wm[w].K / 32);
        wtrans_k<<<g, 256, 0, stream>>>((const float*)d_in[wm[w].src],
                                        WT + wm[w].dst, wm[w].K, wm[w].N);
    }
    lens_k<<<4, 256, 0, stream>>>(ends, lens);

    auto gemmL = [&](const ushort_t* A, int agrp, long long astr, const ushort_t* Bt,
                     ushort_t* C, int M, int N, int K, int relu) {
        dim3 g(N / 128, M / 128);
        mfma_gemm<128, 128, 2, 2><<<g, 256, 0, stream>>>(A, agrp, astr, Bt, C, M, N, K, relu);
    };
    // phase-2 GEMMs: 32x64 tiles -> 800/3200 blocks (rule: need >=400 blocks)
    auto gemmP2 = [&](const ushort_t* A, int agrp, long long astr, const ushort_t* Bt,
                      ushort_t* C, int M, int N, int K, int relu) {
        dim3 g(N / 64, M / 32);
        mfma_gemm<32, 64, 1, 4><<<g, 256, 0, stream>>>(A, agrp, astr, Bt, C, M, N, K, relu);
    };

    // ---------------- Phase 1: all encoders, chunks of G segments ----------
    const int Mc = NB * G * SEGL;
    for (int c = 0; c < NT / G; ++c) {
        const int t0 = c * G;
        const ushort_t* Abase = SEQB + (long long)t0 * SEGL * DMODEL;
        ushort_t* ENCc = ENC + (long long)t0 * SEGL * DMODEL;
        gemmL(Abase, G * SEGL, SEQROW, eWinT, BUF0, Mc, 512, 512, 0);
        gemmL(BUF0, Mc, 0, WQKVe, QKV, Mc, 1536, 512, 0);
        attn_mfma_k<<<NB * G * NHEAD, 256, 0, stream>>>(
            QKV, 50LL * 1536, 1536, QKV + 512, QKV + 1024, 50LL * 1536, 1536,
            BUF4, lens, G, t0);
        gemmL(BUF4, Mc, 0, eWoT, BUF1, Mc, 512, 512, 0);
        add_ln_k<false><<<Mc / 4, 256, 0, stream>>>(BUF0, Mc, 0, BUF1, eG1, eB1,
                                                    BUF2, Mc, 0, Mc);
        gemmL(BUF2, Mc, 0, eF1T, MID, Mc, 2048, 512, 1);
        gemmL(MID, Mc, 0, eF2T, BUF1, Mc, 512, 2048, 0);
        add_ln_k<false><<<Mc / 4, 256, 0, stream>>>(BUF2, Mc, 0, BUF1, eG2, eB2,
                                                    ENCc, G * SEGL, SEQROW, Mc);
    }

    // Batched Q projections for ALL phase-2 steps
    gemmL(ENC + 25600, 750, SEQROW, cWqT, QALL, 48000, 512, 512, 0);

    // ---------------- Phase 2: 15 sequential steps, 6 launches each --------
    const int Ms = NB * SEGL;   // 3200
    for (int t = 1; t < NT; ++t) {
        const ushort_t* currA = ENC + (long long)t * SEGL * DMODEL;
        const ushort_t* prevA; int pg; long long ps;
        if (t == 1) { prevA = ENC;  pg = SEGL; ps = SEQROW; }
        else        { prevA = OUTB; pg = Ms;   ps = 0; }
        // 1) fused KV-projection + cross-attention -> BUF4
        cross_attn_k<<<NB * NHEAD, 256, 0, stream>>>(
            QALL + (long long)(t - 1) * 25600, 750LL * 512, 512,
            prevA, pg, ps, cKV, BUF4);
        // 2) Wo GEMM (800 blocks) -> BUF0
        gemmP2(BUF4, Ms, 0, cWoT, BUF0, Ms, 512, 512, 0);
        // 3) LN(curr + BUF0) -> BUF2
        add_ln_k<false><<<Ms / 4, 256, 0, stream>>>(currA, SEGL, SEQROW, BUF0, cG1, cB1,
                                                    BUF2, Ms, 0, Ms);
        // 4) F1 GEMM + relu (3200 blocks) -> MID
        gemmP2(BUF2, Ms, 0, cF1T, MID, Ms, 2048, 512, 1);
        // 5) F2 GEMM (800 blocks) -> BUF0
        gemmP2(MID, Ms, 0, cF2T, BUF0, Ms, 512, 2048, 0);
        // 6) LN(BUF2 + BUF0) -> OUTB (f32 out on last step)
        if (t == NT - 1)
            add_ln_k<true><<<Ms / 4, 256, 0, stream>>>(BUF2, Ms, 0, BUF0, cG2, cB2,
                                                       out, Ms, 0, Ms);
        else
            add_ln_k<false><<<Ms / 4, 256, 0, stream>>>(BUF2, Ms, 0, BUF0, cG2, cB2,
                                                        OUTB, Ms, 0, Ms);
    }
}

// Round 8
// 2830.540 us; speedup vs baseline: 3.8248x; 1.1401x over previous
//
#include <hip/hip_runtime.h>

// RecurrentTransformerEncoder on MI355X — round 16: round-0 (2770us, verified
// fastest) + split-K for the two low-parallelism phase-2 GEMMs. Wo (K=512)
// and F2 (K=2048) keep 64x64 output tiles but slice K over blockIdx.z
// (Wo: 2 slices -> 800 blocks/4 k-iters; F2: 4 slices -> 1600 blocks/8
// k-iters), writing f32 partials; the add+LN kernels sum the partials (f32,
// numerically >= old bf16 path). Lesson history: <400-block grids are
// latency-crushed (r12-14), thin 32-row tiles lose (r15), grid barriers cost
// 26-65us (r9-11). Launch count unchanged. B=64,T=16,SEG=50,D=512,H=8,F=2048.

#define NB   64
#define NT   16
#define SEGL 50
#define DMODEL 512
#define DFF  2048
#define NHEAD 8
#define DHEAD 64

typedef unsigned short ushort_t;
typedef __attribute__((ext_vector_type(8))) short bfrag;   // 8 bf16 (4 VGPRs)
typedef __attribute__((ext_vector_type(4))) float ffrag;   // 4 fp32 acc

__device__ __forceinline__ ushort_t f2b(float x) {
    union { float f; unsigned u; } c; c.f = x;
    unsigned r = c.u + 0x7fffu + ((c.u >> 16) & 1u);
    return (ushort_t)(r >> 16);
}

#define GLOAD_LDS16(g, l) __builtin_amdgcn_global_load_lds( \
    (const __attribute__((address_space(1))) void*)(g),      \
    (__attribute__((address_space(3))) void*)(l), 16, 0, 0)

#define MFMA16(a, b, c) __builtin_amdgcn_mfma_f32_16x16x32_bf16(a, b, c, 0, 0, 0)

// ---------------------------------------------------------------------------
// MFMA GEMM (LDS-staged, BK=64 dbuf): C = relu?(A @ Bt^T), bf16.
// A rows remapped: row m at A + (m/agrp)*astride + (m%agrp)*K.
// ---------------------------------------------------------------------------
template<int BM, int BN, int WROWS, int WCOLS>
__global__ __launch_bounds__(256) void mfma_gemm(
    const ushort_t* __restrict__ A, int agrp, long long astride,
    const ushort_t* __restrict__ Bt, ushort_t* __restrict__ C,
    int M, int N, int K, int relu)
{
    constexpr int WM = BM / WROWS, WN = BN / WCOLS;
    constexpr int SM = WM / 16, SN = WN / 16;
    constexpr int NSUBA = BM / 16, NSUBB = BN / 16;
    constexpr int NSUB = NSUBA + NSUBB;
    constexpr int NINST = NSUB * 2;
    constexpr int IPW = NINST / 4;
    constexpr int BUFS = NSUB * 1024;
    constexpr int EST = WN + 8;
    constexpr int LDS_KLOOP = 2 * BUFS;
    constexpr int LDS_EPI   = 4 * WM * EST;
    constexpr int LDS_SZ = LDS_KLOOP > LDS_EPI ? LDS_KLOOP : LDS_EPI;
    __shared__ ushort_t lds[LDS_SZ];

    const int tid = threadIdx.x;
    const int wave = tid >> 6, lane = tid & 63;
    const int wrow = wave / WCOLS, wcol = wave % WCOLS;
    const int bm = blockIdx.y * BM, bn = blockIdx.x * BN;
    const int lm = lane & 15, lq = lane >> 4;

    ffrag acc[SM][SN];
#pragma unroll
    for (int i = 0; i < SM; ++i)
#pragma unroll
        for (int j = 0; j < SN; ++j) acc[i][j] = (ffrag){0.f, 0.f, 0.f, 0.f};

    const ushort_t* gptr[IPW];
    int loff[IPW];
#pragma unroll
    for (int e = 0; e < IPW; ++e) {
        int g = wave * IPW + e;
        int s = g >> 1, h = g & 1;
        if (s < NSUBA) {
            int m = bm + s * 16 + lm;
            gptr[e] = A + (long long)(m / agrp) * astride
                        + (long long)(m % agrp) * K + h * 32 + lq * 8;
        } else {
            int n = bn + (s - NSUBA) * 16 + lm;
            gptr[e] = Bt + (long long)n * K + h * 32 + lq * 8;
        }
        loff[e] = s * 1024 + h * 512;
    }

#pragma unroll
    for (int e = 0; e < IPW; ++e)
        GLOAD_LDS16(gptr[e], &lds[loff[e]]);

    const int nk = K >> 6;
    for (int kk = 0; kk < nk; ++kk) {
        __syncthreads();
        if (kk + 1 < nk) {
            const int koff = (kk + 1) << 6;
            const int nb = (kk + 1) & 1;
#pragma unroll
            for (int e = 0; e < IPW; ++e)
                GLOAD_LDS16(gptr[e] + koff, &lds[nb * BUFS + loff[e]]);
        }
        const ushort_t* lb = &lds[(kk & 1) * BUFS];
#pragma unroll
        for (int h = 0; h < 2; ++h) {
            bfrag af[SM], bfg[SN];
#pragma unroll
            for (int i = 0; i < SM; ++i)
                af[i] = *(const bfrag*)&lb[(wrow * SM + i) * 1024 + h * 512 + lane * 8];
#pragma unroll
            for (int j = 0; j < SN; ++j)
                bfg[j] = *(const bfrag*)&lb[(NSUBA + wcol * SN + j) * 1024 + h * 512 + lane * 8];
#pragma unroll
            for (int i = 0; i < SM; ++i)
#pragma unroll
                for (int j = 0; j < SN; ++j)
                    acc[i][j] = MFMA16(af[i], bfg[j], acc[i][j]);
        }
    }

    __syncthreads();
    ushort_t* ep = &lds[wave * WM * EST];
#pragma unroll
    for (int i = 0; i < SM; ++i)
#pragma unroll
        for (int j = 0; j < SN; ++j)
#pragma unroll
            for (int r = 0; r < 4; ++r) {
                int row = i * 16 + lq * 4 + r;
                int col = j * 16 + lm;
                float v = acc[i][j][r];
                if (relu) v = fmaxf(v, 0.f);
                ep[row * EST + col] = f2b(v);
            }
    constexpr int CPR = WN / 8;
    constexpr int RPI = 64 / CPR;
    const int lrow = lane / CPR, lcol = (lane % CPR) * 8;
#pragma unroll
    for (int it = 0; it < WM / RPI; ++it) {
        int row = it * RPI + lrow;
        uint4 v = *(const uint4*)&ep[row * EST + lcol];
        long long grow = bm + wrow * WM + row;
        int gcol = bn + wcol * WN + lcol;
        *(uint4*)&C[grow * N + gcol] = v;
    }
}

// ---------------------------------------------------------------------------
// Split-K 64x64 GEMM, f32 partial output. blockIdx.z = K-slice; slice z
// covers K-range [z*KS, (z+1)*KS). Writes f32 into Cp + z*M*N. Same staging
// structure as mfma_gemm<64,64,2,2> (NSUB=8, IPW=4, 32KB LDS).
// ---------------------------------------------------------------------------
__global__ __launch_bounds__(256) void gemm_sk_k(
    const ushort_t* __restrict__ A, int agrp, long long astride,
    const ushort_t* __restrict__ Bt, float* __restrict__ Cp,
    int M, int N, int K, int KS)
{
    constexpr int BUFS = 8 * 1024;           // 8192 ushorts per buffer
    __shared__ ushort_t lds[2 * BUFS];       // 32768 B; f32 epi needs 20480 B

    const int tid = threadIdx.x;
    const int wave = tid >> 6, lane = tid & 63;
    const int wrow = wave >> 1, wcol = wave & 1;
    const int bm = blockIdx.y * 64, bn = blockIdx.x * 64;
    const int ks0 = blockIdx.z * KS;
    const int lm = lane & 15, lq = lane >> 4;

    ffrag acc[2][2];
#pragma unroll
    for (int i = 0; i < 2; ++i)
#pragma unroll
        for (int j = 0; j < 2; ++j) acc[i][j] = (ffrag){0.f, 0.f, 0.f, 0.f};

    const ushort_t* gptr[4];
    int loff[4];
#pragma unroll
    for (int e = 0; e < 4; ++e) {
        int g = wave * 4 + e;
        int s = g >> 1, h = g & 1;
        if (s < 4) {
            int m = bm + s * 16 + lm;
            gptr[e] = A + (long long)(m / agrp) * astride
                        + (long long)(m % agrp) * K + ks0 + h * 32 + lq * 8;
        } else {
            int n = bn + (s - 4) * 16 + lm;
            gptr[e] = Bt + (long long)n * K + ks0 + h * 32 + lq * 8;
        }
        loff[e] = s * 1024 + h * 512;
    }

#pragma unroll
    for (int e = 0; e < 4; ++e)
        GLOAD_LDS16(gptr[e], &lds[loff[e]]);

    const int nk = KS >> 6;
    for (int kk = 0; kk < nk; ++kk) {
        __syncthreads();
        if (kk + 1 < nk) {
            const int koff = (kk + 1) << 6;
            const int nb = (kk + 1) & 1;
#pragma unroll
            for (int e = 0; e < 4; ++e)
                GLOAD_LDS16(gptr[e] + koff, &lds[nb * BUFS + loff[e]]);
        }
        const ushort_t* lb = &lds[(kk & 1) * BUFS];
#pragma unroll
        for (int h = 0; h < 2; ++h) {
            bfrag af[2], bfg[2];
#pragma unroll
            for (int i = 0; i < 2; ++i)
                af[i] = *(const bfrag*)&lb[(wrow * 2 + i) * 1024 + h * 512 + lane * 8];
#pragma unroll
            for (int j = 0; j < 2; ++j)
                bfg[j] = *(const bfrag*)&lb[(4 + wcol * 2 + j) * 1024 + h * 512 + lane * 8];
#pragma unroll
            for (int i = 0; i < 2; ++i)
#pragma unroll
                for (int j = 0; j < 2; ++j)
                    acc[i][j] = MFMA16(af[i], bfg[j], acc[i][j]);
        }
    }

    __syncthreads();   // staging reads done; reuse LDS as f32 epilogue buffer
    float* ep = (float*)lds + wave * 32 * 40;   // 32 rows x 40 f32 per wave
#pragma unroll
    for (int i = 0; i < 2; ++i)
#pragma unroll
        for (int j = 0; j < 2; ++j)
#pragma unroll
            for (int r = 0; r < 4; ++r)
                ep[(i * 16 + lq * 4 + r) * 40 + j * 16 + lm] = acc[i][j][r];
    // same-wave LDS write->read: ordered, no barrier needed
    float* Cs = Cp + (long long)blockIdx.z * M * N;
    const int lrow = lane >> 3, lcol = (lane & 7) * 4;
#pragma unroll
    for (int it = 0; it < 4; ++it) {
        int row = it * 8 + lrow;
        long long grow = bm + wrow * 32 + row;
        int gcol = bn + wcol * 32 + lcol;
        *(float4*)&Cs[grow * N + gcol] = *(const float4*)&ep[row * 40 + lcol];
    }
}

// ---------------------------------------------------------------------------
// out = LN(res + sum_{p<P} partial_p)*gamma + beta. res bf16 (remapped rows),
// partials f32 (P buffers of M*512 at Pp + p*psz). 4 rows/block.
// ---------------------------------------------------------------------------
template<int P, bool OUTF32>
__global__ __launch_bounds__(256) void add_ln_p_k(
    const ushort_t* __restrict__ Res, int agrp, long long astride,
    const float* __restrict__ Pp,
    const float* __restrict__ gamma, const float* __restrict__ beta,
    void* __restrict__ O, int M)
{
    const int wave = threadIdx.x >> 6, lane = threadIdx.x & 63;
    const int r = blockIdx.x * 4 + wave;
    if (r >= M) return;
    const long long psz = (long long)M * DMODEL;
    const ushort_t* a = Res + (long long)(r / agrp) * astride + (long long)(r % agrp) * DMODEL;
    float x[8];
    {
        uint4 a4 = *(const uint4*)(a + lane * 8);
        const unsigned* aa = (const unsigned*)&a4;
#pragma unroll
        for (int c = 0; c < 4; ++c) {
            union { unsigned u; float f; } alo, ahi;
            alo.u = aa[c] << 16; ahi.u = aa[c] & 0xffff0000u;
            x[2 * c]     = alo.f;
            x[2 * c + 1] = ahi.f;
        }
    }
#pragma unroll
    for (int p = 0; p < P; ++p) {
        const float* q = Pp + p * psz + (long long)r * DMODEL + lane * 8;
        float4 q0 = *(const float4*)q;
        float4 q1 = *(const float4*)(q + 4);
        x[0] += q0.x; x[1] += q0.y; x[2] += q0.z; x[3] += q0.w;
        x[4] += q1.x; x[5] += q1.y; x[6] += q1.z; x[7] += q1.w;
    }
    float s = 0.f, s2 = 0.f;
#pragma unroll
    for (int i = 0; i < 8; ++i) { s += x[i]; s2 = fmaf(x[i], x[i], s2); }
    for (int off = 32; off; off >>= 1) {
        s += __shfl_xor(s, off);
        s2 += __shfl_xor(s2, off);
    }
    const float mean = s * (1.f / DMODEL);
    const float var = s2 * (1.f / DMODEL) - mean * mean;
    const float inv = rsqrtf(var + 1e-5f);
    float4 g0 = *(const float4*)(gamma + lane * 8);
    float4 g1 = *(const float4*)(gamma + lane * 8 + 4);
    float4 e0 = *(const float4*)(beta + lane * 8);
    float4 e1 = *(const float4*)(beta + lane * 8 + 4);
    float y[8];
    y[0] = (x[0] - mean) * inv * g0.x + e0.x;
    y[1] = (x[1] - mean) * inv * g0.y + e0.y;
    y[2] = (x[2] - mean) * inv * g0.z + e0.z;
    y[3] = (x[3] - mean) * inv * g0.w + e0.w;
    y[4] = (x[4] - mean) * inv * g1.x + e1.x;
    y[5] = (x[5] - mean) * inv * g1.y + e1.y;
    y[6] = (x[6] - mean) * inv * g1.z + e1.z;
    y[7] = (x[7] - mean) * inv * g1.w + e1.w;
    if (OUTF32) {
        float* o = (float*)O + (long long)r * DMODEL + lane * 8;
        *(float4*)o = *(float4*)&y[0];
        *(float4*)(o + 4) = *(float4*)&y[4];
    } else {
        ushort_t* o = (ushort_t*)O + (long long)r * DMODEL + lane * 8;
        ushort_t ob[8];
#pragma unroll
        for (int i = 0; i < 8; ++i) ob[i] = f2b(y[i]);
        *(uint4*)o = *(const uint4*)ob;
    }
}

// ---------------------------------------------------------------------------
__global__ __launch_bounds__(256) void wtrans_k(
    const float* __restrict__ W, ushort_t* __restrict__ Wt, int K, int N)
{
    __shared__ float t[32][33];
    const int bk = blockIdx.y * 32, bn = blockIdx.x * 32;
    const int tx = threadIdx.x & 31, ty = threadIdx.x >> 5;
    for (int i = ty; i < 32; i += 8)
        t[i][tx] = W[(long long)(bk + i) * N + bn + tx];
    __syncthreads();
    for (int i = ty; i < 32; i += 8)
        Wt[(long long)(bn + i) * K + bk + tx] = f2b(t[tx][i]);
}

__global__ __launch_bounds__(256) void cvt_k(
    const float* __restrict__ in, ushort_t* __restrict__ out, long long n)
{
    long long i = ((long long)blockIdx.x * 256 + threadIdx.x) * 8;
    if (i >= n) return;
    float4 a = *(const float4*)(in + i);
    float4 b = *(const float4*)(in + i + 4);
    ushort_t o[8] = {f2b(a.x), f2b(a.y), f2b(a.z), f2b(a.w),
                     f2b(b.x), f2b(b.y), f2b(b.z), f2b(b.w)};
    *(uint4*)(out + i) = *(const uint4*)o;
}

// ---------------------------------------------------------------------------
// Phase-1 MFMA attention, one (sequence n, head h) per block. S=50->64, D=64.
// ---------------------------------------------------------------------------
__global__ __launch_bounds__(256) void attn_mfma_k(
    const ushort_t* __restrict__ Q, long long qns, long long qrs,
    const ushort_t* __restrict__ K, const ushort_t* __restrict__ V,
    long long kns, long long kvrs,
    ushort_t* __restrict__ O,
    const int* __restrict__ lens, int G, int t0)
{
    __shared__ ushort_t qs[64][72];   // Q, then P
    __shared__ ushort_t ks[64][72];
    __shared__ ushort_t vt[64][72];   // V^T
    const int n = blockIdx.x >> 3, h = blockIdx.x & 7;
    const int tid = threadIdx.x;
    const int wave = tid >> 6, lane = tid & 63;
    const int lm = lane & 15, lq = lane >> 4;
    int len = SEGL;
    if (lens) {
        int b = n / G, t = t0 + (n % G);
        len = lens[b * NT + t];
        if (len > SEGL) len = SEGL;
    }
    {
        uint4 z = {0, 0, 0, 0};
        uint4* vz = (uint4*)&vt[0][0];
        for (int i = tid; i < 64 * 72 / 8; i += 256) vz[i] = z;
    }
    __syncthreads();
    for (int idx = tid; idx < SEGL * 8; idx += 256) {
        int s = idx >> 3, d8 = (idx & 7) << 3;
        const ushort_t* qp = Q + (long long)n * qns + (long long)s * qrs + h * DHEAD + d8;
        const ushort_t* kp = K + (long long)n * kns + (long long)s * kvrs + h * DHEAD + d8;
        const ushort_t* vp = V + (long long)n * kns + (long long)s * kvrs + h * DHEAD + d8;
        *(uint4*)&qs[s][d8] = *(const uint4*)qp;
        *(uint4*)&ks[s][d8] = *(const uint4*)kp;
        uint4 v4 = *(const uint4*)vp;
        const ushort_t* vv = (const ushort_t*)&v4;
#pragma unroll
        for (int u = 0; u < 8; ++u) vt[d8 + u][s] = vv[u];
    }
    __syncthreads();

    ffrag sc[4];
#pragma unroll
    for (int nt = 0; nt < 4; ++nt) sc[nt] = (ffrag){0.f, 0.f, 0.f, 0.f};
#pragma unroll
    for (int kt = 0; kt < 2; ++kt) {
        bfrag a = *(const bfrag*)&qs[wave * 16 + lm][kt * 32 + lq * 8];
#pragma unroll
        for (int nt = 0; nt < 4; ++nt) {
            bfrag b = *(const bfrag*)&ks[nt * 16 + lm][kt * 32 + lq * 8];
            sc[nt] = MFMA16(a, b, sc[nt]);
        }
    }
    __syncthreads();

#pragma unroll
    for (int r = 0; r < 4; ++r) {
        float x[4];
        float mx = -1e30f;
#pragma unroll
        for (int nt = 0; nt < 4; ++nt) {
            int col = nt * 16 + lm;
            x[nt] = (col < len) ? sc[nt][r] * 0.125f : -1e9f;
            mx = fmaxf(mx, x[nt]);
        }
        for (int off = 8; off; off >>= 1) mx = fmaxf(mx, __shfl_xor(mx, off));
        float e[4], se = 0.f;
#pragma unroll
        for (int nt = 0; nt < 4; ++nt) { e[nt] = __expf(x[nt] - mx); se += e[nt]; }
        for (int off = 8; off; off >>= 1) se += __shfl_xor(se, off);
        float inv = 1.f / se;
        int row = wave * 16 + lq * 4 + r;
#pragma unroll
        for (int nt = 0; nt < 4; ++nt)
            qs[row][nt * 16 + lm] = f2b(e[nt] * inv);
    }
    __syncthreads();

    ffrag oc[4];
#pragma unroll
    for (int dt = 0; dt < 4; ++dt) oc[dt] = (ffrag){0.f, 0.f, 0.f, 0.f};
#pragma unroll
    for (int kt = 0; kt < 2; ++kt) {
        bfrag a = *(const bfrag*)&qs[wave * 16 + lm][kt * 32 + lq * 8];
#pragma unroll
        for (int dt = 0; dt < 4; ++dt) {
            bfrag b = *(const bfrag*)&vt[dt * 16 + lm][kt * 32 + lq * 8];
            oc[dt] = MFMA16(a, b, oc[dt]);
        }
    }
#pragma unroll
    for (int r = 0; r < 4; ++r) {
        int i = wave * 16 + lq * 4 + r;
        if (i < SEGL) {
            ushort_t* op = O + (long long)(n * SEGL + i) * DMODEL + h * DHEAD + lm;
#pragma unroll
            for (int dt = 0; dt < 4; ++dt)
                op[dt * 16] = f2b(oc[dt][r]);
        }
    }
}

// ---------------------------------------------------------------------------
// Phase-2 fused KV-projection + cross-attention. One (seq n, head h) block.
// ---------------------------------------------------------------------------
__global__ __launch_bounds__(256) void cross_attn_k(
    const ushort_t* __restrict__ Qp, long long qns, long long qrs,
    const ushort_t* __restrict__ Prev, int pgrp, long long pstride,
    const ushort_t* __restrict__ Wkv,   // [1024][512] bf16 (cWk^T | cWv^T)
    ushort_t* __restrict__ O)
{
    __shared__ ushort_t xp[64 * 264];   // phase A: prev half; phase B: ks|vt
    __shared__ ushort_t qs[64][72];     // Q, then P
    const int n = blockIdx.x >> 3, h = blockIdx.x & 7;
    const int tid = threadIdx.x;
    const int wave = tid >> 6, lane = tid & 63;
    const int lm = lane & 15, lq = lane >> 4;

    // load Q rows
    for (int idx = tid; idx < SEGL * 8; idx += 256) {
        int s = idx >> 3, d8 = (idx & 7) << 3;
        *(uint4*)&qs[s][d8] =
            *(const uint4*)(Qp + (long long)n * qns + (long long)s * qrs + h * DHEAD + d8);
    }

    // KV projection: wave 0/1 -> K cols 0-31/32-63; wave 2/3 -> V cols.
    const ushort_t* wbase = Wkv +
        (long long)((wave >> 1) * 512 + h * 64 + (wave & 1) * 32) * 512;
    ffrag kv[4][2];
#pragma unroll
    for (int i = 0; i < 4; ++i)
#pragma unroll
        for (int j = 0; j < 2; ++j) kv[i][j] = (ffrag){0.f, 0.f, 0.f, 0.f};

#pragma unroll
    for (int half = 0; half < 2; ++half) {
        __syncthreads();   // prior reads of xp done
        for (int idx = tid; idx < 64 * 33; idx += 256) {
            int s = idx / 33, c8 = (idx % 33) * 8;
            uint4 v = {0, 0, 0, 0};
            if (s < SEGL && c8 < 256) {
                long long r = (long long)n * SEGL + s;
                v = *(const uint4*)(Prev + (r / pgrp) * pstride
                                    + (r % pgrp) * DMODEL + half * 256 + c8);
            }
            *(uint4*)&xp[s * 264 + c8] = v;
        }
        __syncthreads();
#pragma unroll
        for (int k8 = 0; k8 < 8; ++k8) {
            const int kg = half * 256 + k8 * 32;
            bfrag bf[2], af[4];
#pragma unroll
            for (int j = 0; j < 2; ++j)
                bf[j] = *(const bfrag*)(wbase + (long long)(j * 16 + lm) * 512 + kg + lq * 8);
#pragma unroll
            for (int i = 0; i < 4; ++i)
                af[i] = *(const bfrag*)&xp[(i * 16 + lm) * 264 + k8 * 32 + lq * 8];
#pragma unroll
            for (int i = 0; i < 4; ++i)
#pragma unroll
                for (int j = 0; j < 2; ++j)
                    kv[i][j] = MFMA16(af[i], bf[j], kv[i][j]);
        }
    }
    __syncthreads();   // all xp reads done before ks/vt overwrite
    ushort_t (*ks)[72] = (ushort_t(*)[72])&xp[0];
    ushort_t (*vt)[72] = (ushort_t(*)[72])&xp[64 * 72];
#pragma unroll
    for (int i = 0; i < 4; ++i)
#pragma unroll
        for (int j = 0; j < 2; ++j)
#pragma unroll
            for (int r = 0; r < 4; ++r) {
                int rowk = i * 16 + lq * 4 + r;
                int d = (wave & 1) * 32 + j * 16 + lm;
                ushort_t val = f2b(kv[i][j][r]);
                if (wave < 2) ks[rowk][d] = val;   // K[rowk][d]
                else          vt[d][rowk] = val;   // V^T[d][rowk]
            }
    __syncthreads();

    // QK^T
    ffrag sc[4];
#pragma unroll
    for (int nt = 0; nt < 4; ++nt) sc[nt] = (ffrag){0.f, 0.f, 0.f, 0.f};
#pragma unroll
    for (int kt = 0; kt < 2; ++kt) {
        bfrag a = *(const bfrag*)&qs[wave * 16 + lm][kt * 32 + lq * 8];
#pragma unroll
        for (int nt = 0; nt < 4; ++nt) {
            bfrag b = *(const bfrag*)&ks[nt * 16 + lm][kt * 32 + lq * 8];
            sc[nt] = MFMA16(a, b, sc[nt]);
        }
    }
    __syncthreads();

#pragma unroll
    for (int r = 0; r < 4; ++r) {
        float x[4];
        float mx = -1e30f;
#pragma unroll
        for (int nt = 0; nt < 4; ++nt) {
            int col = nt * 16 + lm;
            x[nt] = (col < SEGL) ? sc[nt][r] * 0.125f : -1e9f;
            mx = fmaxf(mx, x[nt]);
        }
        for (int off = 8; off; off >>= 1) mx = fmaxf(mx, __shfl_xor(mx, off));
        float e[4], se = 0.f;
#pragma unroll
        for (int nt = 0; nt < 4; ++nt) { e[nt] = __expf(x[nt] - mx); se += e[nt]; }
        for (int off = 8; off; off >>= 1) se += __shfl_xor(se, off);
        float inv = 1.f / se;
        int row = wave * 16 + lq * 4 + r;
#pragma unroll
        for (int nt = 0; nt < 4; ++nt)
            qs[row][nt * 16 + lm] = f2b(e[nt] * inv);
    }
    __syncthreads();

    // PV
    ffrag oc[4];
#pragma unroll
    for (int dt = 0; dt < 4; ++dt) oc[dt] = (ffrag){0.f, 0.f, 0.f, 0.f};
#pragma unroll
    for (int kt = 0; kt < 2; ++kt) {
        bfrag a = *(const bfrag*)&qs[wave * 16 + lm][kt * 32 + lq * 8];
#pragma unroll
        for (int dt = 0; dt < 4; ++dt) {
            bfrag b = *(const bfrag*)&vt[dt * 16 + lm][kt * 32 + lq * 8];
            oc[dt] = MFMA16(a, b, oc[dt]);
        }
    }
#pragma unroll
    for (int r = 0; r < 4; ++r) {
        int i = wave * 16 + lq * 4 + r;
        if (i < SEGL) {
            ushort_t* op = O + (long long)(n * SEGL + i) * DMODEL + h * DHEAD + lm;
#pragma unroll
            for (int dt = 0; dt < 4; ++dt)
                op[dt * 16] = f2b(oc[dt][r]);
        }
    }
}

// ---------------------------------------------------------------------------
// out = LN(a + b)*gamma + beta, rows of 512, bf16 in, bf16/fp32 out. (phase 1)
// ---------------------------------------------------------------------------
template<bool OUTF32>
__global__ __launch_bounds__(256) void add_ln_k(
    const ushort_t* __restrict__ A, int agrp, long long astride,
    const ushort_t* __restrict__ Bv,
    const float* __restrict__ gamma, const float* __restrict__ beta,
    void* __restrict__ O, int ogrp, long long ostride, int M)
{
    const int wave = threadIdx.x >> 6, lane = threadIdx.x & 63;
    const int r = blockIdx.x * 4 + wave;
    if (r >= M) return;
    const ushort_t* a = A + (long long)(r / agrp) * astride + (long long)(r % agrp) * DMODEL;
    const ushort_t* b = Bv + (long long)r * DMODEL;
    float x[8];
    {
        uint4 a4 = *(const uint4*)(a + lane * 8);
        uint4 b4 = *(const uint4*)(b + lane * 8);
        const unsigned* aa = (const unsigned*)&a4;
        const unsigned* bb = (const unsigned*)&b4;
#pragma unroll
        for (int c = 0; c < 4; ++c) {
            union { unsigned u; float f; } alo, ahi, blo, bhi;
            alo.u = aa[c] << 16; ahi.u = aa[c] & 0xffff0000u;
            blo.u = bb[c] << 16; bhi.u = bb[c] & 0xffff0000u;
            x[2 * c]     = alo.f + blo.f;
            x[2 * c + 1] = ahi.f + bhi.f;
        }
    }
    float s = 0.f, s2 = 0.f;
#pragma unroll
    for (int i = 0; i < 8; ++i) { s += x[i]; s2 = fmaf(x[i], x[i], s2); }
    for (int off = 32; off; off >>= 1) {
        s += __shfl_xor(s, off);
        s2 += __shfl_xor(s2, off);
    }
    const float mean = s * (1.f / DMODEL);
    const float var = s2 * (1.f / DMODEL) - mean * mean;
    const float inv = rsqrtf(var + 1e-5f);
    float4 g0 = *(const float4*)(gamma + lane * 8);
    float4 g1 = *(const float4*)(gamma + lane * 8 + 4);
    float4 be0 = *(const float4*)(beta + lane * 8);
    float4 be1 = *(const float4*)(beta + lane * 8 + 4);
    float y[8];
    y[0] = (x[0] - mean) * inv * g0.x + be0.x;
    y[1] = (x[1] - mean) * inv * g0.y + be0.y;
    y[2] = (x[2] - mean) * inv * g0.z + be0.z;
    y[3] = (x[3] - mean) * inv * g0.w + be0.w;
    y[4] = (x[4] - mean) * inv * g1.x + be1.x;
    y[5] = (x[5] - mean) * inv * g1.y + be1.y;
    y[6] = (x[6] - mean) * inv * g1.z + be1.z;
    y[7] = (x[7] - mean) * inv * g1.w + be1.w;
    if (OUTF32) {
        float* o = (float*)O + (long long)(r / ogrp) * ostride + (long long)(r % ogrp) * DMODEL;
        *(float4*)(o + lane * 8) = *(float4*)&y[0];
        *(float4*)(o + lane * 8 + 4) = *(float4*)&y[4];
    } else {
        ushort_t* o = (ushort_t*)O + (long long)(r / ogrp) * ostride + (long long)(r % ogrp) * DMODEL;
        ushort_t ob[8];
#pragma unroll
        for (int i = 0; i < 8; ++i) ob[i] = f2b(y[i]);
        *(uint4*)(o + lane * 8) = *(const uint4*)ob;
    }
}

__global__ void lens_k(const int* __restrict__ ends, int* __restrict__ lens)
{
    int i = blockIdx.x * 256 + threadIdx.x;
    if (i >= NB * NT) return;
    int t = i & (NT - 1);
    int prev = t ? ends[i - 1] : 0;
    int l = ends[i] - prev;
    if (l > SEGL) l = SEGL;
    lens[i] = l;
}

// ---------------------------------------------------------------------------
extern "C" void kernel_launch(void* const* d_in, const int* in_sizes, int n_in,
                              void* d_out, int out_size, void* d_ws, size_t ws_size,
                              hipStream_t stream)
{
    const float* seqs = (const float*)d_in[0];
    const int*   ends = (const int*)d_in[1];
    const float* eG1 = (const float*)d_in[7],  *eB1 = (const float*)d_in[8];
    const float* eG2 = (const float*)d_in[11], *eB2 = (const float*)d_in[12];
    const float* cG1 = (const float*)d_in[17], *cB1 = (const float*)d_in[18];
    const float* cG2 = (const float*)d_in[21], *cB2 = (const float*)d_in[22];
    float* out = (float*)d_out;

    const int G = (ws_size >= (size_t)470000000) ? 8 : 4;
    const long long CH = 1638400LL * G;

    ushort_t* ws = (ushort_t*)d_ws;
    const long long SEQROW = (long long)NT * SEGL * DMODEL;    // 409600
    ushort_t* SEQB = ws;
    ushort_t* WT   = SEQB + 26214400LL;
    ushort_t* ENC  = WT   + 6553600LL;
    ushort_t* BUF0 = ENC  + 26214400LL;
    ushort_t* QKV  = BUF0 + CH;
    ushort_t* BUF4 = QKV  + 3 * CH;
    ushort_t* BUF1 = BUF4 + CH;
    ushort_t* BUF2 = BUF1 + CH;
    ushort_t* MID  = BUF2 + CH;
    ushort_t* OUTB = MID  + 4 * CH;
    ushort_t* QALL = OUTB + 1638400LL;
    int*      lens = (int*)(QALL + 24576000LL);

    const ushort_t* eWinT = WT + 0;
    const ushort_t* WQKVe = WT + 262144;      // 1536 x 512
    const ushort_t* eWoT  = WT + 1048576;
    const ushort_t* eF1T  = WT + 1310720;     // 2048 x 512
    const ushort_t* eF2T  = WT + 2359296;     // 512 x 2048
    const ushort_t* cWqT  = WT + 3407872;
    const ushort_t* cKV   = WT + 3670016;     // 1024 x 512 (cWk^T | cWv^T)
    const ushort_t* cWoT  = WT + 4194304;
    const ushort_t* cF1T  = WT + 4456448;
    const ushort_t* cF2T  = WT + 5505024;

    // Split-K f32 partial buffers:
    //   Wo: 2 slices x 3200x512 f32 = 13.1 MB -> BUF0 region (CH ushorts >= 13.1 MB for G>=4)
    //   F2: 4 slices x 3200x512 f32 = 26.2 MB -> MID + 3200*2048 (MID is 4*CH; F1 out uses 6.55M ushorts)
    float* WoP = (float*)BUF0;
    float* F2P = (float*)(MID + 3200LL * 2048);

    struct WMap { int src; long long dst; int K, N; };
    const WMap wm[13] = {
        {2,  0,       512, 512},
        {3,  262144,  512, 512},
        {4,  524288,  512, 512},
        {5,  786432,  512, 512},
        {6,  1048576, 512, 512},
        {9,  1310720, 512, 2048},
        {10, 2359296, 2048, 512},
        {13, 3407872, 512, 512},
        {14, 3670016, 512, 512},
        {15, 3932160, 512, 512},
        {16, 4194304, 512, 512},
        {19, 4456448, 512, 2048},
        {20, 5505024, 2048, 512},
    };

    cvt_k<<<12800, 256, 0, stream>>>(seqs, SEQB, 26214400LL);
    for (int w = 0; w < 13; ++w) {
        dim3 g(wm[w].N / 32, wm[w].K / 32);
        wtrans_k<<<g, 256, 0, stream>>>((const float*)d_in[wm[w].src],
                                        WT + wm[w].dst, wm[w].K, wm[w].N);
    }
    lens_k<<<4, 256, 0, stream>>>(ends, lens);

    auto gemmL = [&](const ushort_t* A, int agrp, long long astr, const ushort_t* Bt,
                     ushort_t* C, int M, int N, int K, int relu) {
        dim3 g(N / 128, M / 128);
        mfma_gemm<128, 128, 2, 2><<<g, 256, 0, stream>>>(A, agrp, astr, Bt, C, M, N, K, relu);
    };
    // phase-2 F1 GEMM: 64x64 tiles (proven round-8 config)
    auto gemmS = [&](const ushort_t* A, int agrp, long long astr, const ushort_t* Bt,
                     ushort_t* C, int M, int N, int K, int relu) {
        dim3 g(N / 64, M / 64);
        mfma_gemm<64, 64, 2, 2><<<g, 256, 0, stream>>>(A, agrp, astr, Bt, C, M, N, K, relu);
    };

    // ---------------- Phase 1: all encoders, chunks of G segments ----------
    const int Mc = NB * G * SEGL;
    for (int c = 0; c < NT / G; ++c) {
        const int t0 = c * G;
        const ushort_t* Abase = SEQB + (long long)t0 * SEGL * DMODEL;
        ushort_t* ENCc = ENC + (long long)t0 * SEGL * DMODEL;
        gemmL(Abase, G * SEGL, SEQROW, eWinT, BUF0, Mc, 512, 512, 0);
        gemmL(BUF0, Mc, 0, WQKVe, QKV, Mc, 1536, 512, 0);
        attn_mfma_k<<<NB * G * NHEAD, 256, 0, stream>>>(
            QKV, 50LL * 1536, 1536, QKV + 512, QKV + 1024, 50LL * 1536, 1536,
            BUF4, lens, G, t0);
        gemmL(BUF4, Mc, 0, eWoT, BUF1, Mc, 512, 512, 0);
        add_ln_k<false><<<Mc / 4, 256, 0, stream>>>(BUF0, Mc, 0, BUF1, eG1, eB1,
                                                    BUF2, Mc, 0, Mc);
        gemmL(BUF2, Mc, 0, eF1T, MID, Mc, 2048, 512, 1);
        gemmL(MID, Mc, 0, eF2T, BUF1, Mc, 512, 2048, 0);
        add_ln_k<false><<<Mc / 4, 256, 0, stream>>>(BUF2, Mc, 0, BUF1, eG2, eB2,
                                                    ENCc, G * SEGL, SEQROW, Mc);
    }

    // Batched Q projections for ALL phase-2 steps
    gemmL(ENC + 25600, 750, SEQROW, cWqT, QALL, 48000, 512, 512, 0);

    // ---------------- Phase 2: 15 sequential steps, 6 launches each --------
    const int Ms = NB * SEGL;   // 3200
    for (int t = 1; t < NT; ++t) {
        const ushort_t* currA = ENC + (long long)t * SEGL * DMODEL;
        const ushort_t* prevA; int pg; long long ps;
        if (t == 1) { prevA = ENC;  pg = SEGL; ps = SEQROW; }
        else        { prevA = OUTB; pg = Ms;   ps = 0; }
        // 1) fused KV-projection + cross-attention -> BUF4
        cross_attn_k<<<NB * NHEAD, 256, 0, stream>>>(
            QALL + (long long)(t - 1) * 25600, 750LL * 512, 512,
            prevA, pg, ps, cKV, BUF4);
        // 2) Wo GEMM, split-K 2 (800 blocks, 4 k-iters) -> WoP f32 partials
        gemm_sk_k<<<dim3(512 / 64, Ms / 64, 2), 256, 0, stream>>>(
            BUF4, Ms, 0, cWoT, WoP, Ms, 512, 512, 256);
        // 3) LN(curr + sum WoP) -> BUF2
        add_ln_p_k<2, false><<<Ms / 4, 256, 0, stream>>>(
            currA, SEGL, SEQROW, WoP, cG1, cB1, BUF2, Ms);
        // 4) F1 GEMM + relu (1600 blocks) -> MID
        gemmS(BUF2, Ms, 0, cF1T, MID, Ms, 2048, 512, 1);
        // 5) F2 GEMM, split-K 4 (1600 blocks, 8 k-iters) -> F2P f32 partials
        gemm_sk_k<<<dim3(512 / 64, Ms / 64, 4), 256, 0, stream>>>(
            MID, Ms, 0, cF2T, F2P, Ms, 512, 2048, 512);
        // 6) LN(BUF2 + sum F2P) -> OUTB (f32 out on last step)
        if (t == NT - 1)
            add_ln_p_k<4, true><<<Ms / 4, 256, 0, stream>>>(
                BUF2, Ms, 0, F2P, cG2, cB2, out, Ms);
        else
            add_ln_p_k<4, false><<<Ms / 4, 256, 0, stream>>>(
                BUF2, Ms, 0, F2P, cG2, cB2, OUTB, Ms);
    }
}